// Round 18
// baseline (892.409 us; speedup 1.0000x reference)
//
#include <hip/hip_runtime.h>

// TemporalCausalMaps on MI355X (gfx950), round 21.
// Base = round 20 (verified best, 870.5us: fused gru_proj + hoisted proj-z).
// One structural change: TWO-LAYER GRU SOFTWARE PIPELINE.
//   r20 ran rec-L0 (L serial steps) -> SYNC -> gates-L1 -> SYNC -> rec-L1
//   (L serial steps): 2L dependent ~150cy steps. But layer-1's chain for
//   row t needs only layer-0's output row t. Pipelined loop: iteration tt
//   issues {rec-L0 step tt} and {gates-L1 row + rec-L1 step} for tt-1 —
//   two independent dep chains the scheduler interleaves -> serial depth
//   L+1 instead of 2L (+ gates stage), and 2 fewer SYNCs.
//   (Differs from r18's failed fusion: that injected redundant-phase DS
//   work; this removes true serial depth.)
// LDS unchanged (19456B, 8 blocks/CU): s_gi1 aliases the dead-during-GRU
// s_d1 region; s_hidB aliases s_zz (idx==0-only staging).
// __launch_bounds__(64,1): pipe live set ~150 VGPR > the (64,2) 128 cap;
// 256 cap still admits 2 waves/SIMD (grid supplies exactly 2).

#define NT 64
#define SYNC() asm volatile("s_waitcnt lgkmcnt(0)" ::: "memory")

__device__ __forceinline__ float sigm(float x) { return 1.0f / (1.0f + __expf(-x)); }
__device__ __forceinline__ float tanh_fast(float x) {
  x = fminf(15.0f, fmaxf(-15.0f, x));
  float e = __expf(2.0f * x);
  return (e - 1.0f) / (e + 1.0f);
}
__device__ __forceinline__ float leaky(float x) { return x >= 0.0f ? x : 0.01f * x; }

template <int N4>
__device__ __forceinline__ float dotv2(const float* __restrict__ w, const float* h) {
  const float4* w4 = reinterpret_cast<const float4*>(w);
  const float4* h4 = reinterpret_cast<const float4*>(h);
  float a0 = 0.0f, a1 = 0.0f;
#pragma unroll
  for (int i = 0; i < N4; i += 2) {
    float4 x0 = w4[i], y0 = h4[i];
    float4 x1 = w4[i + 1], y1 = h4[i + 1];
    a0 = fmaf(x0.x, y0.x, a0); a0 = fmaf(x0.y, y0.y, a0);
    a0 = fmaf(x0.z, y0.z, a0); a0 = fmaf(x0.w, y0.w, a0);
    a1 = fmaf(x1.x, y1.x, a1); a1 = fmaf(x1.y, y1.y, a1);
    a1 = fmaf(x1.z, y1.z, a1); a1 = fmaf(x1.w, y1.w, a1);
  }
  return a0 + a1;
}

template <int N4>
__device__ __forceinline__ float dotv4(const float* __restrict__ w, const float* h) {
  const float4* w4 = reinterpret_cast<const float4*>(w);
  const float4* h4 = reinterpret_cast<const float4*>(h);
  float a0 = 0.0f, a1 = 0.0f, a2 = 0.0f, a3 = 0.0f;
#pragma unroll
  for (int i = 0; i < N4; i += 4) {
    float4 x0 = w4[i], y0 = h4[i];
    float4 x1 = w4[i + 1], y1 = h4[i + 1];
    float4 x2 = w4[i + 2], y2 = h4[i + 2];
    float4 x3 = w4[i + 3], y3 = h4[i + 3];
    a0 = fmaf(x0.x, y0.x, a0); a0 = fmaf(x0.y, y0.y, a0);
    a0 = fmaf(x0.z, y0.z, a0); a0 = fmaf(x0.w, y0.w, a0);
    a1 = fmaf(x1.x, y1.x, a1); a1 = fmaf(x1.y, y1.y, a1);
    a1 = fmaf(x1.z, y1.z, a1); a1 = fmaf(x1.w, y1.w, a1);
    a2 = fmaf(x2.x, y2.x, a2); a2 = fmaf(x2.y, y2.y, a2);
    a2 = fmaf(x2.z, y2.z, a2); a2 = fmaf(x2.w, y2.w, a2);
    a3 = fmaf(x3.x, y3.x, a3); a3 = fmaf(x3.y, y3.y, a3);
    a3 = fmaf(x3.w, y3.w, a3); a3 = fmaf(x3.z, y3.z, a3);
  }
  return (a0 + a1) + (a2 + a3);
}

// ---- weight loaders (prefetch points) ----
__device__ __forceinline__ void load_gates_w(
    const float* __restrict__ wih, const float* __restrict__ bih,
    int lane, int rowB, float4 WA[6], float4 WB[6], float& bA, float& bB) {
  const float4* wa = reinterpret_cast<const float4*>(wih + (size_t)lane * 24);
  const float4* wb = reinterpret_cast<const float4*>(wih + (size_t)rowB * 24);
#pragma unroll
  for (int i = 0; i < 6; ++i) { WA[i] = wa[i]; WB[i] = wb[i]; }
  bA = bih[lane]; bB = bih[rowB];
}

__device__ __forceinline__ void load_rec_w(
    const float* __restrict__ whh, const float* __restrict__ bhh,
    int jq, int half, float4 Wr[3], float4 Wz[3], float4 Wn[3],
    float& bR, float& bZ, float& bN) {
  const float4* wr = reinterpret_cast<const float4*>(whh + jq * 24 + half * 12);
  const float4* wz = reinterpret_cast<const float4*>(whh + (24 + jq) * 24 + half * 12);
  const float4* wn = reinterpret_cast<const float4*>(whh + (48 + jq) * 24 + half * 12);
#pragma unroll
  for (int i = 0; i < 3; ++i) { Wr[i] = wr[i]; Wz[i] = wz[i]; Wn[i] = wn[i]; }
  bR = half ? 0.0f : bhh[jq];
  bZ = half ? 0.0f : bhh[24 + jq];
  bN = half ? 0.0f : bhh[48 + jq];
}

// ---- gates (batch form, used for L0 only): lane = row, t-pair ILP ----
__device__ __forceinline__ void gates_comp(
    const float4 WA[6], const float4 WB[6], float bA, float bB,
    const float* srcp, float* s_gi, int L, int lane) {
  int t = 0;
#pragma unroll 1
  for (; t + 1 < L; t += 2) {
    const float4* h0 = reinterpret_cast<const float4*>(srcp + t * 24);
    const float4* h1 = reinterpret_cast<const float4*>(srcp + t * 24 + 24);
    float a0 = bA, a1 = bA, c0 = bB, c1 = bB;
#pragma unroll
    for (int i = 0; i < 6; ++i) {
      float4 p = h0[i], q = h1[i], A = WA[i], Bv = WB[i];
      a0 = fmaf(A.x, p.x, a0); a0 = fmaf(A.y, p.y, a0);
      a0 = fmaf(A.z, p.z, a0); a0 = fmaf(A.w, p.w, a0);
      a1 = fmaf(A.x, q.x, a1); a1 = fmaf(A.y, q.y, a1);
      a1 = fmaf(A.z, q.z, a1); a1 = fmaf(A.w, q.w, a1);
      c0 = fmaf(Bv.x, p.x, c0); c0 = fmaf(Bv.y, p.y, c0);
      c0 = fmaf(Bv.z, p.z, c0); c0 = fmaf(Bv.w, p.w, c0);
      c1 = fmaf(Bv.x, q.x, c1); c1 = fmaf(Bv.y, q.y, c1);
      c1 = fmaf(Bv.z, q.z, c1); c1 = fmaf(Bv.w, q.w, c1);
    }
    s_gi[t * 72 + lane] = a0;
    s_gi[t * 72 + 72 + lane] = a1;
    if (lane < 8) {
      s_gi[t * 72 + 64 + lane] = c0;
      s_gi[t * 72 + 136 + lane] = c1;
    }
  }
  if (t < L) {
    const float4* h0 = reinterpret_cast<const float4*>(srcp + t * 24);
    float a0 = bA, c0 = bB;
#pragma unroll
    for (int i = 0; i < 6; ++i) {
      float4 p = h0[i], A = WA[i], Bv = WB[i];
      a0 = fmaf(A.x, p.x, a0); a0 = fmaf(A.y, p.y, a0);
      a0 = fmaf(A.z, p.z, a0); a0 = fmaf(A.w, p.w, a0);
      c0 = fmaf(Bv.x, p.x, c0); c0 = fmaf(Bv.y, p.y, c0);
      c0 = fmaf(Bv.z, p.z, c0); c0 = fmaf(Bv.w, p.w, c0);
    }
    s_gi[t * 72 + lane] = a0;
    if (lane < 8) s_gi[t * 72 + 64 + lane] = c0;
  }
}

// one gates row (pipe form): rows 0..63 on lanes, rows 64..71 on lanes 0..7
__device__ __forceinline__ void gates_row(
    const float4 WA[6], const float4 WB[6], float bA, float bB,
    const float* src_row, float* gi_row, int lane) {
  const float4* h0 = reinterpret_cast<const float4*>(src_row);
  float a0 = bA, c0 = bB;
#pragma unroll
  for (int i = 0; i < 6; ++i) {
    float4 p = h0[i], A = WA[i], Bv = WB[i];
    a0 = fmaf(A.x, p.x, a0); a0 = fmaf(A.y, p.y, a0);
    a0 = fmaf(A.z, p.z, a0); a0 = fmaf(A.w, p.w, a0);
    c0 = fmaf(Bv.x, p.x, c0); c0 = fmaf(Bv.y, p.y, c0);
    c0 = fmaf(Bv.z, p.z, c0); c0 = fmaf(Bv.w, p.w, c0);
  }
  gi_row[lane] = a0;
  if (lane < 8) gi_row[64 + lane] = c0;
}

// one half-split rec step (identical math to r8/r20's rec_comp body)
__device__ __forceinline__ void rec_step(
    const float4 Wr[3], const float4 Wz[3], const float4 Wn[3],
    float bR, float bZ, float bN, const float* gi_row,
    float* s_hid, int cur, float* y_row, int lane, int jq, int half) {
  const float4* hp = reinterpret_cast<const float4*>(s_hid + cur * 24 + half * 12);
  float gr = bR, gz = bZ, gn = bN;
#pragma unroll
  for (int i = 0; i < 3; ++i) {
    float4 hh = hp[i];
    gr = fmaf(Wr[i].x, hh.x, gr); gr = fmaf(Wr[i].y, hh.y, gr);
    gr = fmaf(Wr[i].z, hh.z, gr); gr = fmaf(Wr[i].w, hh.w, gr);
    gz = fmaf(Wz[i].x, hh.x, gz); gz = fmaf(Wz[i].y, hh.y, gz);
    gz = fmaf(Wz[i].z, hh.z, gz); gz = fmaf(Wz[i].w, hh.w, gz);
    gn = fmaf(Wn[i].x, hh.x, gn); gn = fmaf(Wn[i].y, hh.y, gn);
    gn = fmaf(Wn[i].z, hh.z, gn); gn = fmaf(Wn[i].w, hh.w, gn);
  }
  gr += __shfl_xor(gr, 32);
  gz += __shfl_xor(gz, 32);
  gn += __shfl_xor(gn, 32);
  float r   = sigm(gi_row[jq] + gr);
  float zg  = sigm(gi_row[24 + jq] + gz);
  float nn2 = tanh_fast(gi_row[48 + jq] + r * gn);
  float hold = s_hid[cur * 24 + jq];
  float hnew = fmaf(zg, hold - nn2, nn2);  // (1-z)*n + z*h
  if (lane < 24) {
    s_hid[(cur ^ 1) * 24 + lane] = hnew;
    y_row[lane] = hnew;
  }
}

// ---- pre-kernel: fused gates-L0 weights per node into workspace ----
__global__ void fuse_kernel(const float* __restrict__ gru_wih,
                            const float* __restrict__ gru_bih,
                            const float* __restrict__ gpw,
                            const float* __restrict__ gpb,
                            float* __restrict__ fw, float* __restrict__ fb) {
  const int n = blockIdx.x;
  const int tid = threadIdx.x;
  const float* w = gru_wih + (size_t)(n * 2) * 1728;  // layer 0
  for (int it = tid; it < 1728; it += 64) {
    int r = it / 24, k = it - r * 24;
    float acc = 0.0f;
#pragma unroll
    for (int j = 0; j < 24; ++j) acc = fmaf(w[r * 24 + j], gpw[j * 24 + k], acc);
    fw[(size_t)n * 1728 + it] = acc;
  }
  for (int r = tid; r < 72; r += 64) {
    float acc = gru_bih[(n * 2) * 72 + r];
#pragma unroll
    for (int j = 0; j < 24; ++j) acc = fmaf(w[r * 24 + j], gpb[j], acc);
    fb[n * 72 + r] = acc;
  }
}

// LDS layout (floats). Total 4832 floats = 19,328 B (unchanged vs r20).
//  s_e   [8][16]   @0      s_h  [8][24] @128    s_gi0 [8][72] @320
//  s_y   [8][24]   @896    s_hidA[2][24] @1088  s_d1 [8][68] @1136
//  s_d2  [8][68]   @1680   s_dd [16]    @2224   s_ch [8][36] @2240
//  s_emb [8][8][8] @2528   s_pz [8][8][24] @3040  s_zz [8][32] @4576
//  ALIASES: s_gi1 = @1136 (576 fl over s_d1 + s_d2[0:32]; dead during GRU)
//           s_hidB = @4576 (48 fl of s_zz; s_zz used only pre-GRU at idx=0)
__global__ __launch_bounds__(NT, 1) void tcm_kernel(
    const float* __restrict__ z,
    const float* __restrict__ cond_w1, const float* __restrict__ cond_b1,
    const float* __restrict__ cond_w2, const float* __restrict__ cond_b2,
    const float* __restrict__ proj_w, const float* __restrict__ proj_b,
    const float* __restrict__ gru_wih, const float* __restrict__ gru_whh,
    const float* __restrict__ gru_bih, const float* __restrict__ gru_bhh,
    const float* __restrict__ cm_w1, const float* __restrict__ cm_b1,
    const float* __restrict__ cm_w2, const float* __restrict__ cm_b2,
    const float* __restrict__ cm_w3, const float* __restrict__ cm_b3,
    const int* __restrict__ endw,
    const float* __restrict__ fw, const float* __restrict__ fb,
    float* __restrict__ out, int Btot) {
  __shared__ __align__(16) float lds[4832];
  float* s_e    = lds;          // [8][16]
  float* s_h    = lds + 128;    // [8][24]
  float* s_gi0  = lds + 320;    // [8][72]
  float* s_y    = lds + 896;    // [8][24]
  float* s_hidA = lds + 1088;   // [2][24]
  float* s_d1   = lds + 1136;   // stride 68
  float* s_d2   = lds + 1680;   // stride 68
  float* s_dd   = lds + 2224;
  float* s_ch   = lds + 2240;   // stride 36
  float* s_emb  = lds + 2528;   // [n][t][c]
  float* s_pz   = lds + 3040;   // [n][t][j]
  float* s_zz   = lds + 4576;   // [8][32] staging (idx==0 only)
  float* s_gi1  = lds + 1136;   // alias (GRU-phase only)
  float* s_hidB = lds + 4576;   // alias (GRU-phase only)

  const int lane = threadIdx.x;
  const int b = blockIdx.x;
  const int T = endw[0];
  const int jm = lane & 31;
  const int half = lane >> 5;
  const int jq = jm < 24 ? jm : 0;
  const int rowB = 64 + (lane & 7);

#pragma unroll 1
  for (int idx = 0; idx < T; ++idx) {
    const int L = idx + 1;
#pragma unroll 1
    for (int n = 0; n < 8; ++n) {
      const float* wih1 = gru_wih + (size_t)(n * 2 + 1) * 1728;
      const float* whh0 = gru_whh + (size_t)(n * 2) * 1728;
      const float* whh1 = whh0 + 1728;
      const float* bih1 = gru_bih + (n * 2 + 1) * 72;
      const float* bhh0 = gru_bhh + (n * 2) * 72;
      const float* bhh1 = bhh0 + 72;

      // prefetch FUSED gates-L0 weights (used after proj)
      float4 WA[6], WB[6]; float bA, bB;
      load_gates_w(fw + (size_t)n * 1728, fb + n * 72, lane, rowB, WA, WB, bA, bB);

      // ---- idx==0: hoist proj's z-contribution for ALL 8 t rows
      if (idx == 0) {
        const float4* z4 = reinterpret_cast<const float4*>(
            z + ((size_t)n * Btot + b) * 8 * 32);
        reinterpret_cast<float4*>(s_zz)[lane] = z4[lane];
        SYNC();
#pragma unroll 1
        for (int it = lane; it < 192; it += NT) {
          int t = it / 24, j = it - t * 24;
          s_pz[n * 192 + t * 24 + j] =
              proj_b[n * 24 + j] +
              dotv2<8>(proj_w + (size_t)(n * 24 + j) * 48, s_zz + t * 32);
        }
      }
      // ---- phase A: s_e = [emb_self | emb_pred]
#pragma unroll 1
      for (int it = lane; it < L * 16; it += NT) {
        int t = it >> 4, c = it & 15;
        float v = 0.0f;
        if (c < 8) {
          if (t < idx) v = s_emb[n * 64 + t * 8 + c];
        } else {
          if (n > 0 && idx > 0) v = s_emb[(n - 1) * 64 + t * 8 + (c - 8)];
        }
        s_e[t * 16 + c] = v;
      }
      SYNC();
      // ---- proj -> leaky (z part from s_pz, emb part 16-wide dot)
#pragma unroll 1
      for (int it = lane; it < L * 24; it += NT) {
        int t = it / 24, j = it - t * 24;
        float acc = s_pz[n * 192 + t * 24 + j] +
                    dotv2<4>(proj_w + (size_t)(n * 24 + j) * 48 + 32, s_e + t * 16);
        s_h[t * 24 + j] = leaky(acc);
      }
      SYNC();
      // prefetch rec-L0 weights (in flight during gates L0)
      float4 Wr0[3], Wz0[3], Wn0[3]; float bR0, bZ0, bN0;
      load_rec_w(whh0, bhh0, jq, half, Wr0, Wz0, Wn0, bR0, bZ0, bN0);
      // ---- gates L0 (fused; consumes s_h)
      gates_comp(WA, WB, bA, bB, s_h, s_gi0, L, lane);
      SYNC();
      // load layer-1 weights (gates + rec) for the pipe
      float4 WA1[6], WB1[6]; float bA1, bB1;
      load_gates_w(wih1, bih1, lane, rowB, WA1, WB1, bA1, bB1);
      float4 Wr1[3], Wz1[3], Wn1[3]; float bR1, bZ1, bN1;
      load_rec_w(whh1, bhh1, jq, half, Wr1, Wz1, Wn1, bR1, bZ1, bN1);
      // ---- TWO-LAYER GRU PIPELINE: chainA = rec-L0 step t;
      //      chainB = gates-L1 row (t-1) + rec-L1 step (t-1).
      //      Within an iteration the chains are independent -> interleave.
      //      rec-L1 overwrites s_y row in place AFTER gates-L1 read it
      //      (in-order DS pipe; compiler preserves aliased order).
      {
        if (lane < 24) { s_hidA[lane] = 0.0f; s_hidB[lane] = 0.0f; }
        int curA = 0, curB = 0;
        // prologue: chain A step 0
        rec_step(Wr0, Wz0, Wn0, bR0, bZ0, bN0, s_gi0, s_hidA, curA,
                 s_y, lane, jq, half);
        curA ^= 1;
#pragma unroll 1
        for (int t = 1; t < L; ++t) {
          // chain A: rec L0 step t
          rec_step(Wr0, Wz0, Wn0, bR0, bZ0, bN0, s_gi0 + t * 72, s_hidA, curA,
                   s_y + t * 24, lane, jq, half);
          curA ^= 1;
          // chain B: layer-1 for row t-1
          gates_row(WA1, WB1, bA1, bB1, s_y + (t - 1) * 24,
                    s_gi1 + (t - 1) * 72, lane);
          rec_step(Wr1, Wz1, Wn1, bR1, bZ1, bN1, s_gi1 + (t - 1) * 72,
                   s_hidB, curB, s_y + (t - 1) * 24, lane, jq, half);
          curB ^= 1;
        }
        // epilogue: chain B for row L-1
        gates_row(WA1, WB1, bA1, bB1, s_y + (L - 1) * 24,
                  s_gi1 + (L - 1) * 72, lane);
        rec_step(Wr1, Wz1, Wn1, bR1, bZ1, bN1, s_gi1 + (L - 1) * 72,
                 s_hidB, curB, s_y + (L - 1) * 24, lane, jq, half);
      }
      SYNC();
      // prefetch cm1 row (exposure accepted; ~300cy/cell)
      float4 C1[6];
      {
        const float4* p = reinterpret_cast<const float4*>(
            cm_w1 + (size_t)(n * 64 + lane) * 24);
#pragma unroll
        for (int i = 0; i < 6; ++i) C1[i] = p[i];
      }
      const float c1b = cm_b1[n * 64 + lane];
      // prefetch cm2 row (in flight during cm1)
      float4 C2[16];
      {
        const float4* p = reinterpret_cast<const float4*>(
            cm_w2 + (size_t)(n * 64 + lane) * 64);
#pragma unroll
        for (int i = 0; i < 16; ++i) C2[i] = p[i];
      }
      const float c2b = cm_b2[n * 64 + lane];
      // ---- cm1: lane = j, t unrolled by 2 (s_d1 overwrites dead s_gi1)
      {
        int t = 0;
#pragma unroll 1
        for (; t + 1 < L; t += 2) {
          const float4* y0 = reinterpret_cast<const float4*>(s_y + t * 24);
          const float4* y1 = reinterpret_cast<const float4*>(s_y + t * 24 + 24);
          float a0 = c1b, a1 = c1b;
#pragma unroll
          for (int i = 0; i < 6; ++i) {
            float4 pp = y0[i], q = y1[i], W = C1[i];
            a0 = fmaf(W.x, pp.x, a0); a0 = fmaf(W.y, pp.y, a0);
            a0 = fmaf(W.z, pp.z, a0); a0 = fmaf(W.w, pp.w, a0);
            a1 = fmaf(W.x, q.x, a1); a1 = fmaf(W.y, q.y, a1);
            a1 = fmaf(W.z, q.z, a1); a1 = fmaf(W.w, q.w, a1);
          }
          s_d1[t * 68 + lane] = fmaxf(a0, 0.0f);
          s_d1[t * 68 + 68 + lane] = fmaxf(a1, 0.0f);
        }
        if (t < L) {
          float acc = c1b;
          const float4* y0 = reinterpret_cast<const float4*>(s_y + t * 24);
#pragma unroll
          for (int i = 0; i < 6; ++i) {
            float4 pp = y0[i], W = C1[i];
            acc = fmaf(W.x, pp.x, acc); acc = fmaf(W.y, pp.y, acc);
            acc = fmaf(W.z, pp.z, acc); acc = fmaf(W.w, pp.w, acc);
          }
          s_d1[t * 68 + lane] = fmaxf(acc, 0.0f);
        }
      }
      SYNC();
      // ---- cm2: lane = j, t unrolled by 2, 2 accs per t
      {
        int t = 0;
#pragma unroll 1
        for (; t + 1 < L; t += 2) {
          const float4* d0 = reinterpret_cast<const float4*>(s_d1 + t * 68);
          const float4* d1 = reinterpret_cast<const float4*>(s_d1 + t * 68 + 68);
          float a0 = c2b, a1 = 0.0f, c0 = c2b, c1 = 0.0f;
#pragma unroll
          for (int i = 0; i < 16; i += 2) {
            float4 W0 = C2[i], W1 = C2[i + 1];
            float4 p0 = d0[i], p1 = d0[i + 1], q0 = d1[i], q1 = d1[i + 1];
            a0 = fmaf(W0.x, p0.x, a0); a0 = fmaf(W0.y, p0.y, a0);
            a0 = fmaf(W0.z, p0.z, a0); a0 = fmaf(W0.w, p0.w, a0);
            a1 = fmaf(W1.x, p1.x, a1); a1 = fmaf(W1.y, p1.y, a1);
            a1 = fmaf(W1.z, p1.z, a1); a1 = fmaf(W1.w, p1.w, a1);
            c0 = fmaf(W0.x, q0.x, c0); c0 = fmaf(W0.y, q0.y, c0);
            c0 = fmaf(W0.z, q0.z, c0); c0 = fmaf(W0.w, q0.w, c0);
            c1 = fmaf(W1.x, q1.x, c1); c1 = fmaf(W1.y, q1.y, c1);
            c1 = fmaf(W1.z, q1.z, c1); c1 = fmaf(W1.w, q1.w, c1);
          }
          s_d2[t * 68 + lane] = fmaxf(a0 + a1, 0.0f);
          s_d2[t * 68 + 68 + lane] = fmaxf(c0 + c1, 0.0f);
        }
        if (t < L) {
          const float4* d0 = reinterpret_cast<const float4*>(s_d1 + t * 68);
          float a0 = c2b, a1 = 0.0f;
#pragma unroll
          for (int i = 0; i < 16; i += 2) {
            float4 W0 = C2[i], W1 = C2[i + 1];
            float4 p0 = d0[i], p1 = d0[i + 1];
            a0 = fmaf(W0.x, p0.x, a0); a0 = fmaf(W0.y, p0.y, a0);
            a0 = fmaf(W0.z, p0.z, a0); a0 = fmaf(W0.w, p0.w, a0);
            a1 = fmaf(W1.x, p1.x, a1); a1 = fmaf(W1.y, p1.y, a1);
            a1 = fmaf(W1.z, p1.z, a1); a1 = fmaf(W1.w, p1.w, a1);
          }
          s_d2[t * 68 + lane] = fmaxf(a0 + a1, 0.0f);
        }
      }
      SYNC();
      // ---- cm3 -> decoded row + emit
      if (lane < L) {
        int t = lane;
        float dv = cm_b3[n] + dotv4<16>(cm_w3 + n * 64, s_d2 + t * 68);
        s_dd[t] = dv;
        if (t == idx)
          out[((size_t)b * T + idx) * 8 + n] = dv;
      }
      SYNC();
      // ---- cond-net ONCE per decoded row -> s_emb[n]
#pragma unroll 1
      for (int it = lane; it < L * 32; it += NT) {
        int t = it >> 5, k = it & 31;
        s_ch[t * 36 + k] =
            fmaxf(fmaf(s_dd[t], cond_w1[n * 32 + k], cond_b1[n * 32 + k]), 0.0f);
      }
      SYNC();
      if (lane < L * 8) {
        int t = lane >> 3, c = lane & 7;
        s_emb[n * 64 + t * 8 + c] =
            cond_b2[n * 8 + c] +
            dotv2<8>(cond_w2 + (size_t)(n * 8 + c) * 32, s_ch + t * 36);
      }
      SYNC();
    }
  }
}

extern "C" void kernel_launch(void* const* d_in, const int* in_sizes, int n_in,
                              void* d_out, int out_size, void* d_ws, size_t ws_size,
                              hipStream_t stream) {
  const float* z       = (const float*)d_in[0];
  const float* cond_w1 = (const float*)d_in[1];
  const float* cond_b1 = (const float*)d_in[2];
  const float* cond_w2 = (const float*)d_in[3];
  const float* cond_b2 = (const float*)d_in[4];
  const float* proj_w  = (const float*)d_in[5];
  const float* proj_b  = (const float*)d_in[6];
  const float* gpw     = (const float*)d_in[7];
  const float* gpb     = (const float*)d_in[8];
  const float* gru_wih = (const float*)d_in[9];
  const float* gru_whh = (const float*)d_in[10];
  const float* gru_bih = (const float*)d_in[11];
  const float* gru_bhh = (const float*)d_in[12];
  const float* cm_w1   = (const float*)d_in[13];
  const float* cm_b1   = (const float*)d_in[14];
  const float* cm_w2   = (const float*)d_in[15];
  const float* cm_b2   = (const float*)d_in[16];
  const float* cm_w3   = (const float*)d_in[17];
  const float* cm_b3   = (const float*)d_in[18];
  const int*   endw    = (const int*)d_in[19];
  float* out = (float*)d_out;

  int Btot = in_sizes[0] / (8 * 8 * 32);  // z: [8, B, 8, 32]

  // workspace: fused gates-L0 weights [8][72][24] + bias [8][72]
  float* fw = (float*)d_ws;            // 8*1728 floats
  float* fb = fw + 8 * 1728;           // 8*72 floats (total 57.6 KB)

  fuse_kernel<<<8, 64, 0, stream>>>(gru_wih, gru_bih, gpw, gpb, fw, fb);

  tcm_kernel<<<Btot, NT, 0, stream>>>(
      z, cond_w1, cond_b1, cond_w2, cond_b2, proj_w, proj_b,
      gru_wih, gru_whh, gru_bih, gru_bhh, cm_w1, cm_b1, cm_w2, cm_b2,
      cm_w3, cm_b3, endw, fw, fb, out, Btot);
}

// Round 19
// 874.707 us; speedup vs baseline: 1.0202x; 1.0202x over previous
//
#include <hip/hip_runtime.h>

// TemporalCausalMaps on MI355X (gfx950), round 22.
// Base = round 20 (verified best, 870.5us: fused gru_proj + hoisted proj-z).
// r21's GRU pipeline reverted (892us — single-wave lgkm counter couples the
// two chains' DS queues; twice-confirmed mechanism, r18+r21).
// One DS-op-count reduction on top of r20 (the lever class that wins):
//   phase-A staging DELETED. proj reads s_emb directly:
//     acc = s_pz[n][t][j]
//         + (t<idx)          ? dot8(proj_w[j]+32, s_emb[n][t])   : 0
//         + (n>0 && idx>0)   ? dot8(proj_w[j]+40, s_emb[n-1][t]) : 0
//   Guards are t/n-uniform; rows 32B-aligned. Removes L*16 LDS writes +
//   L*16 reads + 1 SYNC per cell.

#define NT 64
#define SYNC() asm volatile("s_waitcnt lgkmcnt(0)" ::: "memory")

__device__ __forceinline__ float sigm(float x) { return 1.0f / (1.0f + __expf(-x)); }
__device__ __forceinline__ float tanh_fast(float x) {
  x = fminf(15.0f, fmaxf(-15.0f, x));
  float e = __expf(2.0f * x);
  return (e - 1.0f) / (e + 1.0f);
}
__device__ __forceinline__ float leaky(float x) { return x >= 0.0f ? x : 0.01f * x; }

template <int N4>
__device__ __forceinline__ float dotv2(const float* __restrict__ w, const float* h) {
  const float4* w4 = reinterpret_cast<const float4*>(w);
  const float4* h4 = reinterpret_cast<const float4*>(h);
  float a0 = 0.0f, a1 = 0.0f;
#pragma unroll
  for (int i = 0; i < N4; i += 2) {
    float4 x0 = w4[i], y0 = h4[i];
    float4 x1 = w4[i + 1], y1 = h4[i + 1];
    a0 = fmaf(x0.x, y0.x, a0); a0 = fmaf(x0.y, y0.y, a0);
    a0 = fmaf(x0.z, y0.z, a0); a0 = fmaf(x0.w, y0.w, a0);
    a1 = fmaf(x1.x, y1.x, a1); a1 = fmaf(x1.y, y1.y, a1);
    a1 = fmaf(x1.z, y1.z, a1); a1 = fmaf(x1.w, y1.w, a1);
  }
  return a0 + a1;
}

template <int N4>
__device__ __forceinline__ float dotv4(const float* __restrict__ w, const float* h) {
  const float4* w4 = reinterpret_cast<const float4*>(w);
  const float4* h4 = reinterpret_cast<const float4*>(h);
  float a0 = 0.0f, a1 = 0.0f, a2 = 0.0f, a3 = 0.0f;
#pragma unroll
  for (int i = 0; i < N4; i += 4) {
    float4 x0 = w4[i], y0 = h4[i];
    float4 x1 = w4[i + 1], y1 = h4[i + 1];
    float4 x2 = w4[i + 2], y2 = h4[i + 2];
    float4 x3 = w4[i + 3], y3 = h4[i + 3];
    a0 = fmaf(x0.x, y0.x, a0); a0 = fmaf(x0.y, y0.y, a0);
    a0 = fmaf(x0.z, y0.z, a0); a0 = fmaf(x0.w, y0.w, a0);
    a1 = fmaf(x1.x, y1.x, a1); a1 = fmaf(x1.y, y1.y, a1);
    a1 = fmaf(x1.z, y1.z, a1); a1 = fmaf(x1.w, y1.w, a1);
    a2 = fmaf(x2.x, y2.x, a2); a2 = fmaf(x2.y, y2.y, a2);
    a2 = fmaf(x2.z, y2.z, a2); a2 = fmaf(x2.w, y2.w, a2);
    a3 = fmaf(x3.x, y3.x, a3); a3 = fmaf(x3.y, y3.y, a3);
    a3 = fmaf(x3.w, y3.w, a3); a3 = fmaf(x3.z, y3.z, a3);
  }
  return (a0 + a1) + (a2 + a3);
}

// ---- weight loaders (prefetch points) ----
__device__ __forceinline__ void load_gates_w(
    const float* __restrict__ wih, const float* __restrict__ bih,
    int lane, int rowB, float4 WA[6], float4 WB[6], float& bA, float& bB) {
  const float4* wa = reinterpret_cast<const float4*>(wih + (size_t)lane * 24);
  const float4* wb = reinterpret_cast<const float4*>(wih + (size_t)rowB * 24);
#pragma unroll
  for (int i = 0; i < 6; ++i) { WA[i] = wa[i]; WB[i] = wb[i]; }
  bA = bih[lane]; bB = bih[rowB];
}

__device__ __forceinline__ void load_rec_w(
    const float* __restrict__ whh, const float* __restrict__ bhh,
    int jq, int half, float4 Wr[3], float4 Wz[3], float4 Wn[3],
    float& bR, float& bZ, float& bN) {
  const float4* wr = reinterpret_cast<const float4*>(whh + jq * 24 + half * 12);
  const float4* wz = reinterpret_cast<const float4*>(whh + (24 + jq) * 24 + half * 12);
  const float4* wn = reinterpret_cast<const float4*>(whh + (48 + jq) * 24 + half * 12);
#pragma unroll
  for (int i = 0; i < 3; ++i) { Wr[i] = wr[i]; Wz[i] = wz[i]; Wn[i] = wn[i]; }
  bR = half ? 0.0f : bhh[jq];
  bZ = half ? 0.0f : bhh[24 + jq];
  bN = half ? 0.0f : bhh[48 + jq];
}

// ---- compute stages (weights already in regs) ----
__device__ __forceinline__ void gates_comp(
    const float4 WA[6], const float4 WB[6], float bA, float bB,
    const float* srcp, float* s_gi, int L, int lane) {
  int t = 0;
#pragma unroll 1
  for (; t + 1 < L; t += 2) {
    const float4* h0 = reinterpret_cast<const float4*>(srcp + t * 24);
    const float4* h1 = reinterpret_cast<const float4*>(srcp + t * 24 + 24);
    float a0 = bA, a1 = bA, c0 = bB, c1 = bB;
#pragma unroll
    for (int i = 0; i < 6; ++i) {
      float4 p = h0[i], q = h1[i], A = WA[i], Bv = WB[i];
      a0 = fmaf(A.x, p.x, a0); a0 = fmaf(A.y, p.y, a0);
      a0 = fmaf(A.z, p.z, a0); a0 = fmaf(A.w, p.w, a0);
      a1 = fmaf(A.x, q.x, a1); a1 = fmaf(A.y, q.y, a1);
      a1 = fmaf(A.z, q.z, a1); a1 = fmaf(A.w, q.w, a1);
      c0 = fmaf(Bv.x, p.x, c0); c0 = fmaf(Bv.y, p.y, c0);
      c0 = fmaf(Bv.z, p.z, c0); c0 = fmaf(Bv.w, p.w, c0);
      c1 = fmaf(Bv.x, q.x, c1); c1 = fmaf(Bv.y, q.y, c1);
      c1 = fmaf(Bv.z, q.z, c1); c1 = fmaf(Bv.w, q.w, c1);
    }
    s_gi[t * 72 + lane] = a0;
    s_gi[t * 72 + 72 + lane] = a1;
    if (lane < 8) {
      s_gi[t * 72 + 64 + lane] = c0;
      s_gi[t * 72 + 136 + lane] = c1;
    }
  }
  if (t < L) {
    const float4* h0 = reinterpret_cast<const float4*>(srcp + t * 24);
    float a0 = bA, c0 = bB;
#pragma unroll
    for (int i = 0; i < 6; ++i) {
      float4 p = h0[i], A = WA[i], Bv = WB[i];
      a0 = fmaf(A.x, p.x, a0); a0 = fmaf(A.y, p.y, a0);
      a0 = fmaf(A.z, p.z, a0); a0 = fmaf(A.w, p.w, a0);
      c0 = fmaf(Bv.x, p.x, c0); c0 = fmaf(Bv.y, p.y, c0);
      c0 = fmaf(Bv.z, p.z, c0); c0 = fmaf(Bv.w, p.w, c0);
    }
    s_gi[t * 72 + lane] = a0;
    if (lane < 8) s_gi[t * 72 + 64 + lane] = c0;
  }
}

__device__ __forceinline__ void rec_comp(
    const float4 Wr[3], const float4 Wz[3], const float4 Wn[3],
    float bR, float bZ, float bN,
    const float* s_gi, float* s_hid, float* s_y, int L, int lane, int jq, int half) {
  if (lane < 24) s_hid[lane] = 0.0f;
  int cur = 0;
#pragma unroll 1
  for (int t = 0; t < L; ++t) {
    const float4* hp = reinterpret_cast<const float4*>(s_hid + cur * 24 + half * 12);
    float gr = bR, gz = bZ, gn = bN;
#pragma unroll
    for (int i = 0; i < 3; ++i) {
      float4 hh = hp[i];
      gr = fmaf(Wr[i].x, hh.x, gr); gr = fmaf(Wr[i].y, hh.y, gr);
      gr = fmaf(Wr[i].z, hh.z, gr); gr = fmaf(Wr[i].w, hh.w, gr);
      gz = fmaf(Wz[i].x, hh.x, gz); gz = fmaf(Wz[i].y, hh.y, gz);
      gz = fmaf(Wz[i].z, hh.z, gz); gz = fmaf(Wz[i].w, hh.w, gz);
      gn = fmaf(Wn[i].x, hh.x, gn); gn = fmaf(Wn[i].y, hh.y, gn);
      gn = fmaf(Wn[i].z, hh.z, gn); gn = fmaf(Wn[i].w, hh.w, gn);
    }
    gr += __shfl_xor(gr, 32);
    gz += __shfl_xor(gz, 32);
    gn += __shfl_xor(gn, 32);
    const float* gi = s_gi + t * 72;
    float r   = sigm(gi[jq] + gr);
    float zg  = sigm(gi[24 + jq] + gz);
    float nn2 = tanh_fast(gi[48 + jq] + r * gn);
    float hold = s_hid[cur * 24 + jq];
    float hnew = fmaf(zg, hold - nn2, nn2);  // (1-z)*n + z*h
    if (lane < 24) {
      s_hid[(cur ^ 1) * 24 + lane] = hnew;
      s_y[t * 24 + lane] = hnew;
    }
    cur ^= 1;
  }
}

// ---- pre-kernel: fused gates-L0 weights per node into workspace ----
// fw[n][72][24] = wih0[n] . gpw ; fb[n][72] = bih0[n] + wih0[n] . gpb
__global__ void fuse_kernel(const float* __restrict__ gru_wih,
                            const float* __restrict__ gru_bih,
                            const float* __restrict__ gpw,
                            const float* __restrict__ gpb,
                            float* __restrict__ fw, float* __restrict__ fb) {
  const int n = blockIdx.x;
  const int tid = threadIdx.x;
  const float* w = gru_wih + (size_t)(n * 2) * 1728;  // layer 0
  for (int it = tid; it < 1728; it += 64) {
    int r = it / 24, k = it - r * 24;
    float acc = 0.0f;
#pragma unroll
    for (int j = 0; j < 24; ++j) acc = fmaf(w[r * 24 + j], gpw[j * 24 + k], acc);
    fw[(size_t)n * 1728 + it] = acc;
  }
  for (int r = tid; r < 72; r += 64) {
    float acc = gru_bih[(n * 2) * 72 + r];
#pragma unroll
    for (int j = 0; j < 24; ++j) acc = fmaf(w[r * 24 + j], gpb[j], acc);
    fb[n * 72 + r] = acc;
  }
}

// LDS layout (floats). Total 4832 floats = 19,328 B.
//  (s_e slot retained but unused) @0     s_h  [8][24] @128   s_gi [8][72] @320
//  s_y   [8][24]   @896    s_hid[2][24] @1088   s_d1 [8][68] @1136
//  s_d2  [8][68]   @1680   s_dd [16]    @2224   s_ch [8][36] @2240
//  s_emb [8][8][8] @2528   s_pz [8][8][24] @3040  s_zz [8][32] @4576
__global__ __launch_bounds__(NT, 2) void tcm_kernel(
    const float* __restrict__ z,
    const float* __restrict__ cond_w1, const float* __restrict__ cond_b1,
    const float* __restrict__ cond_w2, const float* __restrict__ cond_b2,
    const float* __restrict__ proj_w, const float* __restrict__ proj_b,
    const float* __restrict__ gru_wih, const float* __restrict__ gru_whh,
    const float* __restrict__ gru_bih, const float* __restrict__ gru_bhh,
    const float* __restrict__ cm_w1, const float* __restrict__ cm_b1,
    const float* __restrict__ cm_w2, const float* __restrict__ cm_b2,
    const float* __restrict__ cm_w3, const float* __restrict__ cm_b3,
    const int* __restrict__ endw,
    const float* __restrict__ fw, const float* __restrict__ fb,
    float* __restrict__ out, int Btot) {
  __shared__ __align__(16) float lds[4832];
  float* s_h   = lds + 128;    // [8][24]
  float* s_gi  = lds + 320;    // [8][72]
  float* s_y   = lds + 896;    // [8][24]
  float* s_hid = lds + 1088;   // [2][24]
  float* s_d1  = lds + 1136;   // stride 68
  float* s_d2  = lds + 1680;   // stride 68
  float* s_dd  = lds + 2224;
  float* s_ch  = lds + 2240;   // stride 36
  float* s_emb = lds + 2528;   // [n][t][c] = n*64 + t*8 + c
  float* s_pz  = lds + 3040;   // [n][t][j] = n*192 + t*24 + j
  float* s_zz  = lds + 4576;   // [8][32] staging (idx==0 only)

  const int lane = threadIdx.x;
  const int b = blockIdx.x;
  const int T = endw[0];
  const int jm = lane & 31;
  const int half = lane >> 5;
  const int jq = jm < 24 ? jm : 0;
  const int rowB = 64 + (lane & 7);

#pragma unroll 1
  for (int idx = 0; idx < T; ++idx) {
    const int L = idx + 1;
#pragma unroll 1
    for (int n = 0; n < 8; ++n) {
      const float* wih1 = gru_wih + (size_t)(n * 2 + 1) * 1728;
      const float* whh0 = gru_whh + (size_t)(n * 2) * 1728;
      const float* whh1 = whh0 + 1728;
      const float* bih1 = gru_bih + (n * 2 + 1) * 72;
      const float* bhh0 = gru_bhh + (n * 2) * 72;
      const float* bhh1 = bhh0 + 72;

      // prefetch FUSED gates-L0 weights (used after proj)
      float4 WA[6], WB[6]; float bA, bB;
      load_gates_w(fw + (size_t)n * 1728, fb + n * 72, lane, rowB, WA, WB, bA, bB);

      // ---- idx==0: hoist proj's z-contribution for ALL 8 t rows
      if (idx == 0) {
        const float4* z4 = reinterpret_cast<const float4*>(
            z + ((size_t)n * Btot + b) * 8 * 32);
        reinterpret_cast<float4*>(s_zz)[lane] = z4[lane];
        SYNC();
#pragma unroll 1
        for (int it = lane; it < 192; it += NT) {
          int t = it / 24, j = it - t * 24;
          s_pz[n * 192 + t * 24 + j] =
              proj_b[n * 24 + j] +
              dotv2<8>(proj_w + (size_t)(n * 24 + j) * 48, s_zz + t * 32);
        }
        SYNC();
      }
      // ---- proj -> leaky: z-part from s_pz; emb-part read DIRECTLY from
      //      s_emb (phase-A staging eliminated). Guards are t/n-uniform.
#pragma unroll 1
      for (int it = lane; it < L * 24; it += NT) {
        int t = it / 24, j = it - t * 24;
        const float* pw = proj_w + (size_t)(n * 24 + j) * 48;
        float acc = s_pz[n * 192 + t * 24 + j];
        if (t < idx)
          acc += dotv2<2>(pw + 32, s_emb + n * 64 + t * 8);
        if (n > 0 && idx > 0)
          acc += dotv2<2>(pw + 40, s_emb + (n - 1) * 64 + t * 8);
        s_h[t * 24 + j] = leaky(acc);
      }
      SYNC();
      // prefetch rec-L0 weights (in flight during gates L0)
      float4 Wr[3], Wz[3], Wn[3]; float bR, bZ, bN;
      load_rec_w(whh0, bhh0, jq, half, Wr, Wz, Wn, bR, bZ, bN);
      // ---- gates L0 (FUSED: consumes s_h directly; gru_proj eliminated)
      gates_comp(WA, WB, bA, bB, s_h, s_gi, L, lane);
      SYNC();
      // prefetch gates-L1 weights (in flight during rec L0)
      float4 WA1[6], WB1[6]; float bA1, bB1;
      load_gates_w(wih1, bih1, lane, rowB, WA1, WB1, bA1, bB1);
      // ---- rec L0 -> s_y
      rec_comp(Wr, Wz, Wn, bR, bZ, bN, s_gi, s_hid, s_y, L, lane, jq, half);
      SYNC();
      // prefetch rec-L1 weights (in flight during gates L1)
      float4 Wr1[3], Wz1[3], Wn1[3]; float bR1, bZ1, bN1;
      load_rec_w(whh1, bhh1, jq, half, Wr1, Wz1, Wn1, bR1, bZ1, bN1);
      // ---- gates L1
      gates_comp(WA1, WB1, bA1, bB1, s_y, s_gi, L, lane);
      SYNC();
      // prefetch cm1 row (in flight during rec L1)
      float4 C1[6];
      {
        const float4* p = reinterpret_cast<const float4*>(
            cm_w1 + (size_t)(n * 64 + lane) * 24);
#pragma unroll
        for (int i = 0; i < 6; ++i) C1[i] = p[i];
      }
      const float c1b = cm_b1[n * 64 + lane];
      // ---- rec L1 -> s_y
      rec_comp(Wr1, Wz1, Wn1, bR1, bZ1, bN1, s_gi, s_hid, s_y, L, lane, jq, half);
      SYNC();
      // prefetch cm2 row (in flight during cm1)
      float4 C2[16];
      {
        const float4* p = reinterpret_cast<const float4*>(
            cm_w2 + (size_t)(n * 64 + lane) * 64);
#pragma unroll
        for (int i = 0; i < 16; ++i) C2[i] = p[i];
      }
      const float c2b = cm_b2[n * 64 + lane];
      // ---- cm1: lane = j, t unrolled by 2
      {
        int t = 0;
#pragma unroll 1
        for (; t + 1 < L; t += 2) {
          const float4* y0 = reinterpret_cast<const float4*>(s_y + t * 24);
          const float4* y1 = reinterpret_cast<const float4*>(s_y + t * 24 + 24);
          float a0 = c1b, a1 = c1b;
#pragma unroll
          for (int i = 0; i < 6; ++i) {
            float4 pp = y0[i], q = y1[i], W = C1[i];
            a0 = fmaf(W.x, pp.x, a0); a0 = fmaf(W.y, pp.y, a0);
            a0 = fmaf(W.z, pp.z, a0); a0 = fmaf(W.w, pp.w, a0);
            a1 = fmaf(W.x, q.x, a1); a1 = fmaf(W.y, q.y, a1);
            a1 = fmaf(W.z, q.z, a1); a1 = fmaf(W.w, q.w, a1);
          }
          s_d1[t * 68 + lane] = fmaxf(a0, 0.0f);
          s_d1[t * 68 + 68 + lane] = fmaxf(a1, 0.0f);
        }
        if (t < L) {
          float acc = c1b;
          const float4* y0 = reinterpret_cast<const float4*>(s_y + t * 24);
#pragma unroll
          for (int i = 0; i < 6; ++i) {
            float4 pp = y0[i], W = C1[i];
            acc = fmaf(W.x, pp.x, acc); acc = fmaf(W.y, pp.y, acc);
            acc = fmaf(W.z, pp.z, acc); acc = fmaf(W.w, pp.w, acc);
          }
          s_d1[t * 68 + lane] = fmaxf(acc, 0.0f);
        }
      }
      SYNC();
      // ---- cm2: lane = j, t unrolled by 2, 2 accs per t
      {
        int t = 0;
#pragma unroll 1
        for (; t + 1 < L; t += 2) {
          const float4* d0 = reinterpret_cast<const float4*>(s_d1 + t * 68);
          const float4* d1 = reinterpret_cast<const float4*>(s_d1 + t * 68 + 68);
          float a0 = c2b, a1 = 0.0f, c0 = c2b, c1 = 0.0f;
#pragma unroll
          for (int i = 0; i < 16; i += 2) {
            float4 W0 = C2[i], W1 = C2[i + 1];
            float4 p0 = d0[i], p1 = d0[i + 1], q0 = d1[i], q1 = d1[i + 1];
            a0 = fmaf(W0.x, p0.x, a0); a0 = fmaf(W0.y, p0.y, a0);
            a0 = fmaf(W0.z, p0.z, a0); a0 = fmaf(W0.w, p0.w, a0);
            a1 = fmaf(W1.x, p1.x, a1); a1 = fmaf(W1.y, p1.y, a1);
            a1 = fmaf(W1.z, p1.z, a1); a1 = fmaf(W1.w, p1.w, a1);
            c0 = fmaf(W0.x, q0.x, c0); c0 = fmaf(W0.y, q0.y, c0);
            c0 = fmaf(W0.z, q0.z, c0); c0 = fmaf(W0.w, q0.w, c0);
            c1 = fmaf(W1.x, q1.x, c1); c1 = fmaf(W1.y, q1.y, c1);
            c1 = fmaf(W1.z, q1.z, c1); c1 = fmaf(W1.w, q1.w, c1);
          }
          s_d2[t * 68 + lane] = fmaxf(a0 + a1, 0.0f);
          s_d2[t * 68 + 68 + lane] = fmaxf(c0 + c1, 0.0f);
        }
        if (t < L) {
          const float4* d0 = reinterpret_cast<const float4*>(s_d1 + t * 68);
          float a0 = c2b, a1 = 0.0f;
#pragma unroll
          for (int i = 0; i < 16; i += 2) {
            float4 W0 = C2[i], W1 = C2[i + 1];
            float4 p0 = d0[i], p1 = d0[i + 1];
            a0 = fmaf(W0.x, p0.x, a0); a0 = fmaf(W0.y, p0.y, a0);
            a0 = fmaf(W0.z, p0.z, a0); a0 = fmaf(W0.w, p0.w, a0);
            a1 = fmaf(W1.x, p1.x, a1); a1 = fmaf(W1.y, p1.y, a1);
            a1 = fmaf(W1.z, p1.z, a1); a1 = fmaf(W1.w, p1.w, a1);
          }
          s_d2[t * 68 + lane] = fmaxf(a0 + a1, 0.0f);
        }
      }
      SYNC();
      // ---- cm3 -> decoded row + emit
      if (lane < L) {
        int t = lane;
        float dv = cm_b3[n] + dotv4<16>(cm_w3 + n * 64, s_d2 + t * 68);
        s_dd[t] = dv;
        if (t == idx)
          out[((size_t)b * T + idx) * 8 + n] = dv;
      }
      SYNC();
      // ---- cond-net ONCE per decoded row -> s_emb[n]
#pragma unroll 1
      for (int it = lane; it < L * 32; it += NT) {
        int t = it >> 5, k = it & 31;
        s_ch[t * 36 + k] =
            fmaxf(fmaf(s_dd[t], cond_w1[n * 32 + k], cond_b1[n * 32 + k]), 0.0f);
      }
      SYNC();
      if (lane < L * 8) {
        int t = lane >> 3, c = lane & 7;
        s_emb[n * 64 + t * 8 + c] =
            cond_b2[n * 8 + c] +
            dotv2<8>(cond_w2 + (size_t)(n * 8 + c) * 32, s_ch + t * 36);
      }
      SYNC();
    }
  }
}

extern "C" void kernel_launch(void* const* d_in, const int* in_sizes, int n_in,
                              void* d_out, int out_size, void* d_ws, size_t ws_size,
                              hipStream_t stream) {
  const float* z       = (const float*)d_in[0];
  const float* cond_w1 = (const float*)d_in[1];
  const float* cond_b1 = (const float*)d_in[2];
  const float* cond_w2 = (const float*)d_in[3];
  const float* cond_b2 = (const float*)d_in[4];
  const float* proj_w  = (const float*)d_in[5];
  const float* proj_b  = (const float*)d_in[6];
  const float* gpw     = (const float*)d_in[7];
  const float* gpb     = (const float*)d_in[8];
  const float* gru_wih = (const float*)d_in[9];
  const float* gru_whh = (const float*)d_in[10];
  const float* gru_bih = (const float*)d_in[11];
  const float* gru_bhh = (const float*)d_in[12];
  const float* cm_w1   = (const float*)d_in[13];
  const float* cm_b1   = (const float*)d_in[14];
  const float* cm_w2   = (const float*)d_in[15];
  const float* cm_b2   = (const float*)d_in[16];
  const float* cm_w3   = (const float*)d_in[17];
  const float* cm_b3   = (const float*)d_in[18];
  const int*   endw    = (const int*)d_in[19];
  float* out = (float*)d_out;

  int Btot = in_sizes[0] / (8 * 8 * 32);  // z: [8, B, 8, 32]

  // workspace: fused gates-L0 weights [8][72][24] + bias [8][72]
  float* fw = (float*)d_ws;            // 8*1728 floats
  float* fb = fw + 8 * 1728;           // 8*72 floats (total 57.6 KB)

  fuse_kernel<<<8, 64, 0, stream>>>(gru_wih, gru_bih, gpw, gpb, fw, fb);

  tcm_kernel<<<Btot, NT, 0, stream>>>(
      z, cond_w1, cond_b1, cond_w2, cond_b2, proj_w, proj_b,
      gru_wih, gru_whh, gru_bih, gru_bhh, cm_w1, cm_b1, cm_w2, cm_b2,
      cm_w3, cm_b3, endw, fw, fb, out, Btot);
}

// Round 20
// 866.179 us; speedup vs baseline: 1.0303x; 1.0098x over previous
//
#include <hip/hip_runtime.h>

// TemporalCausalMaps on MI355X (gfx950), round 23.
// Base = r22 (verified ~874us; = r20 core: fused gru_proj + hoisted proj-z
// + direct-s_emb proj). Final DS-reduction of the winning class:
//   cond-net fused to ONE stage. Lane (t,c) computes
//     emb = b2[c] + sum_k w2[c][k] * relu(dv_t*w1[k] + b1[k])
//   directly from s_dd[t] (w1/b1 lane-uniform -> scalar loads; w2 row
//   vectorized). Removes s_ch staging (L*32 LDS writes + reads) and one
//   SYNC per cell. 8x redundant relu recompute is ~96 cheap VALU ops.
// Session ledger: 1197.7 -> ~870us. Wins were all algebra/DS-reduction
// (r7 ILP+cond-once, r8 lgkm-SYNC+prefetch, r20 fusion+hoist); all
// scheduling/parallelism restructures regressed (stream count grid-capped
// at 2/SIMD; single lgkm counter couples co-resident LDS phases).

#define NT 64
#define SYNC() asm volatile("s_waitcnt lgkmcnt(0)" ::: "memory")

__device__ __forceinline__ float sigm(float x) { return 1.0f / (1.0f + __expf(-x)); }
__device__ __forceinline__ float tanh_fast(float x) {
  x = fminf(15.0f, fmaxf(-15.0f, x));
  float e = __expf(2.0f * x);
  return (e - 1.0f) / (e + 1.0f);
}
__device__ __forceinline__ float leaky(float x) { return x >= 0.0f ? x : 0.01f * x; }

template <int N4>
__device__ __forceinline__ float dotv2(const float* __restrict__ w, const float* h) {
  const float4* w4 = reinterpret_cast<const float4*>(w);
  const float4* h4 = reinterpret_cast<const float4*>(h);
  float a0 = 0.0f, a1 = 0.0f;
#pragma unroll
  for (int i = 0; i < N4; i += 2) {
    float4 x0 = w4[i], y0 = h4[i];
    float4 x1 = w4[i + 1], y1 = h4[i + 1];
    a0 = fmaf(x0.x, y0.x, a0); a0 = fmaf(x0.y, y0.y, a0);
    a0 = fmaf(x0.z, y0.z, a0); a0 = fmaf(x0.w, y0.w, a0);
    a1 = fmaf(x1.x, y1.x, a1); a1 = fmaf(x1.y, y1.y, a1);
    a1 = fmaf(x1.z, y1.z, a1); a1 = fmaf(x1.w, y1.w, a1);
  }
  return a0 + a1;
}

template <int N4>
__device__ __forceinline__ float dotv4(const float* __restrict__ w, const float* h) {
  const float4* w4 = reinterpret_cast<const float4*>(w);
  const float4* h4 = reinterpret_cast<const float4*>(h);
  float a0 = 0.0f, a1 = 0.0f, a2 = 0.0f, a3 = 0.0f;
#pragma unroll
  for (int i = 0; i < N4; i += 4) {
    float4 x0 = w4[i], y0 = h4[i];
    float4 x1 = w4[i + 1], y1 = h4[i + 1];
    float4 x2 = w4[i + 2], y2 = h4[i + 2];
    float4 x3 = w4[i + 3], y3 = h4[i + 3];
    a0 = fmaf(x0.x, y0.x, a0); a0 = fmaf(x0.y, y0.y, a0);
    a0 = fmaf(x0.z, y0.z, a0); a0 = fmaf(x0.w, y0.w, a0);
    a1 = fmaf(x1.x, y1.x, a1); a1 = fmaf(x1.y, y1.y, a1);
    a1 = fmaf(x1.z, y1.z, a1); a1 = fmaf(x1.w, y1.w, a1);
    a2 = fmaf(x2.x, y2.x, a2); a2 = fmaf(x2.y, y2.y, a2);
    a2 = fmaf(x2.z, y2.z, a2); a2 = fmaf(x2.w, y2.w, a2);
    a3 = fmaf(x3.x, y3.x, a3); a3 = fmaf(x3.y, y3.y, a3);
    a3 = fmaf(x3.w, y3.w, a3); a3 = fmaf(x3.z, y3.z, a3);
  }
  return (a0 + a1) + (a2 + a3);
}

// ---- weight loaders (prefetch points) ----
__device__ __forceinline__ void load_gates_w(
    const float* __restrict__ wih, const float* __restrict__ bih,
    int lane, int rowB, float4 WA[6], float4 WB[6], float& bA, float& bB) {
  const float4* wa = reinterpret_cast<const float4*>(wih + (size_t)lane * 24);
  const float4* wb = reinterpret_cast<const float4*>(wih + (size_t)rowB * 24);
#pragma unroll
  for (int i = 0; i < 6; ++i) { WA[i] = wa[i]; WB[i] = wb[i]; }
  bA = bih[lane]; bB = bih[rowB];
}

__device__ __forceinline__ void load_rec_w(
    const float* __restrict__ whh, const float* __restrict__ bhh,
    int jq, int half, float4 Wr[3], float4 Wz[3], float4 Wn[3],
    float& bR, float& bZ, float& bN) {
  const float4* wr = reinterpret_cast<const float4*>(whh + jq * 24 + half * 12);
  const float4* wz = reinterpret_cast<const float4*>(whh + (24 + jq) * 24 + half * 12);
  const float4* wn = reinterpret_cast<const float4*>(whh + (48 + jq) * 24 + half * 12);
#pragma unroll
  for (int i = 0; i < 3; ++i) { Wr[i] = wr[i]; Wz[i] = wz[i]; Wn[i] = wn[i]; }
  bR = half ? 0.0f : bhh[jq];
  bZ = half ? 0.0f : bhh[24 + jq];
  bN = half ? 0.0f : bhh[48 + jq];
}

// ---- compute stages (weights already in regs) ----
__device__ __forceinline__ void gates_comp(
    const float4 WA[6], const float4 WB[6], float bA, float bB,
    const float* srcp, float* s_gi, int L, int lane) {
  int t = 0;
#pragma unroll 1
  for (; t + 1 < L; t += 2) {
    const float4* h0 = reinterpret_cast<const float4*>(srcp + t * 24);
    const float4* h1 = reinterpret_cast<const float4*>(srcp + t * 24 + 24);
    float a0 = bA, a1 = bA, c0 = bB, c1 = bB;
#pragma unroll
    for (int i = 0; i < 6; ++i) {
      float4 p = h0[i], q = h1[i], A = WA[i], Bv = WB[i];
      a0 = fmaf(A.x, p.x, a0); a0 = fmaf(A.y, p.y, a0);
      a0 = fmaf(A.z, p.z, a0); a0 = fmaf(A.w, p.w, a0);
      a1 = fmaf(A.x, q.x, a1); a1 = fmaf(A.y, q.y, a1);
      a1 = fmaf(A.z, q.z, a1); a1 = fmaf(A.w, q.w, a1);
      c0 = fmaf(Bv.x, p.x, c0); c0 = fmaf(Bv.y, p.y, c0);
      c0 = fmaf(Bv.z, p.z, c0); c0 = fmaf(Bv.w, p.w, c0);
      c1 = fmaf(Bv.x, q.x, c1); c1 = fmaf(Bv.y, q.y, c1);
      c1 = fmaf(Bv.z, q.z, c1); c1 = fmaf(Bv.w, q.w, c1);
    }
    s_gi[t * 72 + lane] = a0;
    s_gi[t * 72 + 72 + lane] = a1;
    if (lane < 8) {
      s_gi[t * 72 + 64 + lane] = c0;
      s_gi[t * 72 + 136 + lane] = c1;
    }
  }
  if (t < L) {
    const float4* h0 = reinterpret_cast<const float4*>(srcp + t * 24);
    float a0 = bA, c0 = bB;
#pragma unroll
    for (int i = 0; i < 6; ++i) {
      float4 p = h0[i], A = WA[i], Bv = WB[i];
      a0 = fmaf(A.x, p.x, a0); a0 = fmaf(A.y, p.y, a0);
      a0 = fmaf(A.z, p.z, a0); a0 = fmaf(A.w, p.w, a0);
      c0 = fmaf(Bv.x, p.x, c0); c0 = fmaf(Bv.y, p.y, c0);
      c0 = fmaf(Bv.z, p.z, c0); c0 = fmaf(Bv.w, p.w, c0);
    }
    s_gi[t * 72 + lane] = a0;
    if (lane < 8) s_gi[t * 72 + 64 + lane] = c0;
  }
}

__device__ __forceinline__ void rec_comp(
    const float4 Wr[3], const float4 Wz[3], const float4 Wn[3],
    float bR, float bZ, float bN,
    const float* s_gi, float* s_hid, float* s_y, int L, int lane, int jq, int half) {
  if (lane < 24) s_hid[lane] = 0.0f;
  int cur = 0;
#pragma unroll 1
  for (int t = 0; t < L; ++t) {
    const float4* hp = reinterpret_cast<const float4*>(s_hid + cur * 24 + half * 12);
    float gr = bR, gz = bZ, gn = bN;
#pragma unroll
    for (int i = 0; i < 3; ++i) {
      float4 hh = hp[i];
      gr = fmaf(Wr[i].x, hh.x, gr); gr = fmaf(Wr[i].y, hh.y, gr);
      gr = fmaf(Wr[i].z, hh.z, gr); gr = fmaf(Wr[i].w, hh.w, gr);
      gz = fmaf(Wz[i].x, hh.x, gz); gz = fmaf(Wz[i].y, hh.y, gz);
      gz = fmaf(Wz[i].z, hh.z, gz); gz = fmaf(Wz[i].w, hh.w, gz);
      gn = fmaf(Wn[i].x, hh.x, gn); gn = fmaf(Wn[i].y, hh.y, gn);
      gn = fmaf(Wn[i].z, hh.z, gn); gn = fmaf(Wn[i].w, hh.w, gn);
    }
    gr += __shfl_xor(gr, 32);
    gz += __shfl_xor(gz, 32);
    gn += __shfl_xor(gn, 32);
    const float* gi = s_gi + t * 72;
    float r   = sigm(gi[jq] + gr);
    float zg  = sigm(gi[24 + jq] + gz);
    float nn2 = tanh_fast(gi[48 + jq] + r * gn);
    float hold = s_hid[cur * 24 + jq];
    float hnew = fmaf(zg, hold - nn2, nn2);  // (1-z)*n + z*h
    if (lane < 24) {
      s_hid[(cur ^ 1) * 24 + lane] = hnew;
      s_y[t * 24 + lane] = hnew;
    }
    cur ^= 1;
  }
}

// ---- pre-kernel: fused gates-L0 weights per node into workspace ----
// fw[n][72][24] = wih0[n] . gpw ; fb[n][72] = bih0[n] + wih0[n] . gpb
__global__ void fuse_kernel(const float* __restrict__ gru_wih,
                            const float* __restrict__ gru_bih,
                            const float* __restrict__ gpw,
                            const float* __restrict__ gpb,
                            float* __restrict__ fw, float* __restrict__ fb) {
  const int n = blockIdx.x;
  const int tid = threadIdx.x;
  const float* w = gru_wih + (size_t)(n * 2) * 1728;  // layer 0
  for (int it = tid; it < 1728; it += 64) {
    int r = it / 24, k = it - r * 24;
    float acc = 0.0f;
#pragma unroll
    for (int j = 0; j < 24; ++j) acc = fmaf(w[r * 24 + j], gpw[j * 24 + k], acc);
    fw[(size_t)n * 1728 + it] = acc;
  }
  for (int r = tid; r < 72; r += 64) {
    float acc = gru_bih[(n * 2) * 72 + r];
#pragma unroll
    for (int j = 0; j < 24; ++j) acc = fmaf(w[r * 24 + j], gpb[j], acc);
    fb[n * 72 + r] = acc;
  }
}

// LDS layout (floats). Total 4832 floats = 19,328 B.
//  s_h  [8][24] @128   s_gi [8][72] @320   s_y   [8][24] @896
//  s_hid[2][24] @1088  s_d1 [8][68] @1136  s_d2  [8][68] @1680
//  s_dd [16]    @2224  s_emb[8][8][8] @2528
//  s_pz [8][8][24] @3040   s_zz [8][32] @4576
__global__ __launch_bounds__(NT, 2) void tcm_kernel(
    const float* __restrict__ z,
    const float* __restrict__ cond_w1, const float* __restrict__ cond_b1,
    const float* __restrict__ cond_w2, const float* __restrict__ cond_b2,
    const float* __restrict__ proj_w, const float* __restrict__ proj_b,
    const float* __restrict__ gru_wih, const float* __restrict__ gru_whh,
    const float* __restrict__ gru_bih, const float* __restrict__ gru_bhh,
    const float* __restrict__ cm_w1, const float* __restrict__ cm_b1,
    const float* __restrict__ cm_w2, const float* __restrict__ cm_b2,
    const float* __restrict__ cm_w3, const float* __restrict__ cm_b3,
    const int* __restrict__ endw,
    const float* __restrict__ fw, const float* __restrict__ fb,
    float* __restrict__ out, int Btot) {
  __shared__ __align__(16) float lds[4832];
  float* s_h   = lds + 128;    // [8][24]
  float* s_gi  = lds + 320;    // [8][72]
  float* s_y   = lds + 896;    // [8][24]
  float* s_hid = lds + 1088;   // [2][24]
  float* s_d1  = lds + 1136;   // stride 68
  float* s_d2  = lds + 1680;   // stride 68
  float* s_dd  = lds + 2224;
  float* s_emb = lds + 2528;   // [n][t][c] = n*64 + t*8 + c
  float* s_pz  = lds + 3040;   // [n][t][j] = n*192 + t*24 + j
  float* s_zz  = lds + 4576;   // [8][32] staging (idx==0 only)

  const int lane = threadIdx.x;
  const int b = blockIdx.x;
  const int T = endw[0];
  const int jm = lane & 31;
  const int half = lane >> 5;
  const int jq = jm < 24 ? jm : 0;
  const int rowB = 64 + (lane & 7);

#pragma unroll 1
  for (int idx = 0; idx < T; ++idx) {
    const int L = idx + 1;
#pragma unroll 1
    for (int n = 0; n < 8; ++n) {
      const float* wih1 = gru_wih + (size_t)(n * 2 + 1) * 1728;
      const float* whh0 = gru_whh + (size_t)(n * 2) * 1728;
      const float* whh1 = whh0 + 1728;
      const float* bih1 = gru_bih + (n * 2 + 1) * 72;
      const float* bhh0 = gru_bhh + (n * 2) * 72;
      const float* bhh1 = bhh0 + 72;

      // prefetch FUSED gates-L0 weights (used after proj)
      float4 WA[6], WB[6]; float bA, bB;
      load_gates_w(fw + (size_t)n * 1728, fb + n * 72, lane, rowB, WA, WB, bA, bB);

      // ---- idx==0: hoist proj's z-contribution for ALL 8 t rows
      if (idx == 0) {
        const float4* z4 = reinterpret_cast<const float4*>(
            z + ((size_t)n * Btot + b) * 8 * 32);
        reinterpret_cast<float4*>(s_zz)[lane] = z4[lane];
        SYNC();
#pragma unroll 1
        for (int it = lane; it < 192; it += NT) {
          int t = it / 24, j = it - t * 24;
          s_pz[n * 192 + t * 24 + j] =
              proj_b[n * 24 + j] +
              dotv2<8>(proj_w + (size_t)(n * 24 + j) * 48, s_zz + t * 32);
        }
        SYNC();
      }
      // ---- proj -> leaky: z-part from s_pz; emb-part direct from s_emb
#pragma unroll 1
      for (int it = lane; it < L * 24; it += NT) {
        int t = it / 24, j = it - t * 24;
        const float* pw = proj_w + (size_t)(n * 24 + j) * 48;
        float acc = s_pz[n * 192 + t * 24 + j];
        if (t < idx)
          acc += dotv2<2>(pw + 32, s_emb + n * 64 + t * 8);
        if (n > 0 && idx > 0)
          acc += dotv2<2>(pw + 40, s_emb + (n - 1) * 64 + t * 8);
        s_h[t * 24 + j] = leaky(acc);
      }
      SYNC();
      // prefetch rec-L0 weights (in flight during gates L0)
      float4 Wr[3], Wz[3], Wn[3]; float bR, bZ, bN;
      load_rec_w(whh0, bhh0, jq, half, Wr, Wz, Wn, bR, bZ, bN);
      // ---- gates L0 (FUSED: consumes s_h directly)
      gates_comp(WA, WB, bA, bB, s_h, s_gi, L, lane);
      SYNC();
      // prefetch gates-L1 weights (in flight during rec L0)
      float4 WA1[6], WB1[6]; float bA1, bB1;
      load_gates_w(wih1, bih1, lane, rowB, WA1, WB1, bA1, bB1);
      // ---- rec L0 -> s_y
      rec_comp(Wr, Wz, Wn, bR, bZ, bN, s_gi, s_hid, s_y, L, lane, jq, half);
      SYNC();
      // prefetch rec-L1 weights (in flight during gates L1)
      float4 Wr1[3], Wz1[3], Wn1[3]; float bR1, bZ1, bN1;
      load_rec_w(whh1, bhh1, jq, half, Wr1, Wz1, Wn1, bR1, bZ1, bN1);
      // ---- gates L1
      gates_comp(WA1, WB1, bA1, bB1, s_y, s_gi, L, lane);
      SYNC();
      // prefetch cm1 row (in flight during rec L1)
      float4 C1[6];
      {
        const float4* p = reinterpret_cast<const float4*>(
            cm_w1 + (size_t)(n * 64 + lane) * 24);
#pragma unroll
        for (int i = 0; i < 6; ++i) C1[i] = p[i];
      }
      const float c1b = cm_b1[n * 64 + lane];
      // ---- rec L1 -> s_y
      rec_comp(Wr1, Wz1, Wn1, bR1, bZ1, bN1, s_gi, s_hid, s_y, L, lane, jq, half);
      SYNC();
      // prefetch cm2 row (in flight during cm1)
      float4 C2[16];
      {
        const float4* p = reinterpret_cast<const float4*>(
            cm_w2 + (size_t)(n * 64 + lane) * 64);
#pragma unroll
        for (int i = 0; i < 16; ++i) C2[i] = p[i];
      }
      const float c2b = cm_b2[n * 64 + lane];
      // ---- cm1: lane = j, t unrolled by 2
      {
        int t = 0;
#pragma unroll 1
        for (; t + 1 < L; t += 2) {
          const float4* y0 = reinterpret_cast<const float4*>(s_y + t * 24);
          const float4* y1 = reinterpret_cast<const float4*>(s_y + t * 24 + 24);
          float a0 = c1b, a1 = c1b;
#pragma unroll
          for (int i = 0; i < 6; ++i) {
            float4 pp = y0[i], q = y1[i], W = C1[i];
            a0 = fmaf(W.x, pp.x, a0); a0 = fmaf(W.y, pp.y, a0);
            a0 = fmaf(W.z, pp.z, a0); a0 = fmaf(W.w, pp.w, a0);
            a1 = fmaf(W.x, q.x, a1); a1 = fmaf(W.y, q.y, a1);
            a1 = fmaf(W.z, q.z, a1); a1 = fmaf(W.w, q.w, a1);
          }
          s_d1[t * 68 + lane] = fmaxf(a0, 0.0f);
          s_d1[t * 68 + 68 + lane] = fmaxf(a1, 0.0f);
        }
        if (t < L) {
          float acc = c1b;
          const float4* y0 = reinterpret_cast<const float4*>(s_y + t * 24);
#pragma unroll
          for (int i = 0; i < 6; ++i) {
            float4 pp = y0[i], W = C1[i];
            acc = fmaf(W.x, pp.x, acc); acc = fmaf(W.y, pp.y, acc);
            acc = fmaf(W.z, pp.z, acc); acc = fmaf(W.w, pp.w, acc);
          }
          s_d1[t * 68 + lane] = fmaxf(acc, 0.0f);
        }
      }
      SYNC();
      // ---- cm2: lane = j, t unrolled by 2, 2 accs per t
      {
        int t = 0;
#pragma unroll 1
        for (; t + 1 < L; t += 2) {
          const float4* d0 = reinterpret_cast<const float4*>(s_d1 + t * 68);
          const float4* d1 = reinterpret_cast<const float4*>(s_d1 + t * 68 + 68);
          float a0 = c2b, a1 = 0.0f, c0 = c2b, c1 = 0.0f;
#pragma unroll
          for (int i = 0; i < 16; i += 2) {
            float4 W0 = C2[i], W1 = C2[i + 1];
            float4 p0 = d0[i], p1 = d0[i + 1], q0 = d1[i], q1 = d1[i + 1];
            a0 = fmaf(W0.x, p0.x, a0); a0 = fmaf(W0.y, p0.y, a0);
            a0 = fmaf(W0.z, p0.z, a0); a0 = fmaf(W0.w, p0.w, a0);
            a1 = fmaf(W1.x, p1.x, a1); a1 = fmaf(W1.y, p1.y, a1);
            a1 = fmaf(W1.z, p1.z, a1); a1 = fmaf(W1.w, p1.w, a1);
            c0 = fmaf(W0.x, q0.x, c0); c0 = fmaf(W0.y, q0.y, c0);
            c0 = fmaf(W0.z, q0.z, c0); c0 = fmaf(W0.w, q0.w, c0);
            c1 = fmaf(W1.x, q1.x, c1); c1 = fmaf(W1.y, q1.y, c1);
            c1 = fmaf(W1.z, q1.z, c1); c1 = fmaf(W1.w, q1.w, c1);
          }
          s_d2[t * 68 + lane] = fmaxf(a0 + a1, 0.0f);
          s_d2[t * 68 + 68 + lane] = fmaxf(c0 + c1, 0.0f);
        }
        if (t < L) {
          const float4* d0 = reinterpret_cast<const float4*>(s_d1 + t * 68);
          float a0 = c2b, a1 = 0.0f;
#pragma unroll
          for (int i = 0; i < 16; i += 2) {
            float4 W0 = C2[i], W1 = C2[i + 1];
            float4 p0 = d0[i], p1 = d0[i + 1];
            a0 = fmaf(W0.x, p0.x, a0); a0 = fmaf(W0.y, p0.y, a0);
            a0 = fmaf(W0.z, p0.z, a0); a0 = fmaf(W0.w, p0.w, a0);
            a1 = fmaf(W1.x, p1.x, a1); a1 = fmaf(W1.y, p1.y, a1);
            a1 = fmaf(W1.z, p1.z, a1); a1 = fmaf(W1.w, p1.w, a1);
          }
          s_d2[t * 68 + lane] = fmaxf(a0 + a1, 0.0f);
        }
      }
      SYNC();
      // ---- cm3 -> decoded row + emit
      if (lane < L) {
        int t = lane;
        float dv = cm_b3[n] + dotv4<16>(cm_w3 + n * 64, s_d2 + t * 68);
        s_dd[t] = dv;
        if (t == idx)
          out[((size_t)b * T + idx) * 8 + n] = dv;
      }
      SYNC();
      // ---- cond-net FUSED to one stage: lane (t,c) computes
      //      emb = b2[c] + sum_k w2[c][k]*relu(dv_t*w1[k]+b1[k])
      //      w1/b1 lane-uniform (scalar loads); w2 row 8x float4.
      if (lane < L * 8) {
        int t = lane >> 3, c = lane & 7;
        float dv = s_dd[t];
        const float* w1 = cond_w1 + n * 32;
        const float* b1 = cond_b1 + n * 32;
        const float4* w2 = reinterpret_cast<const float4*>(
            cond_w2 + (size_t)(n * 8 + c) * 32);
        float acc = cond_b2[n * 8 + c];
#pragma unroll
        for (int i = 0; i < 8; ++i) {
          float4 wv = w2[i];
          float h0 = fmaxf(fmaf(dv, w1[4 * i + 0], b1[4 * i + 0]), 0.0f);
          float h1 = fmaxf(fmaf(dv, w1[4 * i + 1], b1[4 * i + 1]), 0.0f);
          float h2 = fmaxf(fmaf(dv, w1[4 * i + 2], b1[4 * i + 2]), 0.0f);
          float h3 = fmaxf(fmaf(dv, w1[4 * i + 3], b1[4 * i + 3]), 0.0f);
          acc = fmaf(wv.x, h0, acc); acc = fmaf(wv.y, h1, acc);
          acc = fmaf(wv.z, h2, acc); acc = fmaf(wv.w, h3, acc);
        }
        s_emb[n * 64 + t * 8 + c] = acc;
      }
      SYNC();
    }
  }
}

extern "C" void kernel_launch(void* const* d_in, const int* in_sizes, int n_in,
                              void* d_out, int out_size, void* d_ws, size_t ws_size,
                              hipStream_t stream) {
  const float* z       = (const float*)d_in[0];
  const float* cond_w1 = (const float*)d_in[1];
  const float* cond_b1 = (const float*)d_in[2];
  const float* cond_w2 = (const float*)d_in[3];
  const float* cond_b2 = (const float*)d_in[4];
  const float* proj_w  = (const float*)d_in[5];
  const float* proj_b  = (const float*)d_in[6];
  const float* gpw     = (const float*)d_in[7];
  const float* gpb     = (const float*)d_in[8];
  const float* gru_wih = (const float*)d_in[9];
  const float* gru_whh = (const float*)d_in[10];
  const float* gru_bih = (const float*)d_in[11];
  const float* gru_bhh = (const float*)d_in[12];
  const float* cm_w1   = (const float*)d_in[13];
  const float* cm_b1   = (const float*)d_in[14];
  const float* cm_w2   = (const float*)d_in[15];
  const float* cm_b2   = (const float*)d_in[16];
  const float* cm_w3   = (const float*)d_in[17];
  const float* cm_b3   = (const float*)d_in[18];
  const int*   endw    = (const int*)d_in[19];
  float* out = (float*)d_out;

  int Btot = in_sizes[0] / (8 * 8 * 32);  // z: [8, B, 8, 32]

  // workspace: fused gates-L0 weights [8][72][24] + bias [8][72]
  float* fw = (float*)d_ws;            // 8*1728 floats
  float* fb = fw + 8 * 1728;           // 8*72 floats (total 57.6 KB)

  fuse_kernel<<<8, 64, 0, stream>>>(gru_wih, gru_bih, gpw, gpb, fw, fb);

  tcm_kernel<<<Btot, NT, 0, stream>>>(
      z, cond_w1, cond_b1, cond_w2, cond_b2, proj_w, proj_b,
      gru_wih, gru_whh, gru_bih, gru_bhh, cm_w1, cm_b1, cm_w2, cm_b2,
      cm_w3, cm_b3, endw, fw, fb, out, Btot);
}

// Round 21
// 866.052 us; speedup vs baseline: 1.0304x; 1.0001x over previous
//
#include <hip/hip_runtime.h>

// TemporalCausalMaps on MI355X (gfx950), round 24.
// Base = r23 (verified best, 866us / medians ~840). Final DS-elimination:
//   cm3 FOLDED into the cond stage. cm3 ran on <=L lanes (<=8 of 64),
//   stored s_dd, SYNC'd, then cond read it. Wave issue cost is per-WAVE,
//   so recomputing dv_t on each (t,c) lane (8x redundant, same s_d2 row =
//   LDS broadcast) costs zero extra wave-issue time vs the serial pair,
//   while deleting the s_dd round-trip + 1 SYNC per cell. out-emit moves
//   into the fused stage (lane c==0, t==idx).
// Ledger: 1197.7 -> ~860us. All wins = algebra/DS-reduction (r7, r8, r20,
// r23, this); all scheduling/parallelism restructures regressed (streams
// grid-capped at 2/SIMD; single lgkm counter couples co-resident phases).

#define NT 64
#define SYNC() asm volatile("s_waitcnt lgkmcnt(0)" ::: "memory")

__device__ __forceinline__ float sigm(float x) { return 1.0f / (1.0f + __expf(-x)); }
__device__ __forceinline__ float tanh_fast(float x) {
  x = fminf(15.0f, fmaxf(-15.0f, x));
  float e = __expf(2.0f * x);
  return (e - 1.0f) / (e + 1.0f);
}
__device__ __forceinline__ float leaky(float x) { return x >= 0.0f ? x : 0.01f * x; }

template <int N4>
__device__ __forceinline__ float dotv2(const float* __restrict__ w, const float* h) {
  const float4* w4 = reinterpret_cast<const float4*>(w);
  const float4* h4 = reinterpret_cast<const float4*>(h);
  float a0 = 0.0f, a1 = 0.0f;
#pragma unroll
  for (int i = 0; i < N4; i += 2) {
    float4 x0 = w4[i], y0 = h4[i];
    float4 x1 = w4[i + 1], y1 = h4[i + 1];
    a0 = fmaf(x0.x, y0.x, a0); a0 = fmaf(x0.y, y0.y, a0);
    a0 = fmaf(x0.z, y0.z, a0); a0 = fmaf(x0.w, y0.w, a0);
    a1 = fmaf(x1.x, y1.x, a1); a1 = fmaf(x1.y, y1.y, a1);
    a1 = fmaf(x1.z, y1.z, a1); a1 = fmaf(x1.w, y1.w, a1);
  }
  return a0 + a1;
}

template <int N4>
__device__ __forceinline__ float dotv4(const float* __restrict__ w, const float* h) {
  const float4* w4 = reinterpret_cast<const float4*>(w);
  const float4* h4 = reinterpret_cast<const float4*>(h);
  float a0 = 0.0f, a1 = 0.0f, a2 = 0.0f, a3 = 0.0f;
#pragma unroll
  for (int i = 0; i < N4; i += 4) {
    float4 x0 = w4[i], y0 = h4[i];
    float4 x1 = w4[i + 1], y1 = h4[i + 1];
    float4 x2 = w4[i + 2], y2 = h4[i + 2];
    float4 x3 = w4[i + 3], y3 = h4[i + 3];
    a0 = fmaf(x0.x, y0.x, a0); a0 = fmaf(x0.y, y0.y, a0);
    a0 = fmaf(x0.z, y0.z, a0); a0 = fmaf(x0.w, y0.w, a0);
    a1 = fmaf(x1.x, y1.x, a1); a1 = fmaf(x1.y, y1.y, a1);
    a1 = fmaf(x1.z, y1.z, a1); a1 = fmaf(x1.w, y1.w, a1);
    a2 = fmaf(x2.x, y2.x, a2); a2 = fmaf(x2.y, y2.y, a2);
    a2 = fmaf(x2.z, y2.z, a2); a2 = fmaf(x2.w, y2.w, a2);
    a3 = fmaf(x3.x, y3.x, a3); a3 = fmaf(x3.y, y3.y, a3);
    a3 = fmaf(x3.w, y3.w, a3); a3 = fmaf(x3.z, y3.z, a3);
  }
  return (a0 + a1) + (a2 + a3);
}

// ---- weight loaders (prefetch points) ----
__device__ __forceinline__ void load_gates_w(
    const float* __restrict__ wih, const float* __restrict__ bih,
    int lane, int rowB, float4 WA[6], float4 WB[6], float& bA, float& bB) {
  const float4* wa = reinterpret_cast<const float4*>(wih + (size_t)lane * 24);
  const float4* wb = reinterpret_cast<const float4*>(wih + (size_t)rowB * 24);
#pragma unroll
  for (int i = 0; i < 6; ++i) { WA[i] = wa[i]; WB[i] = wb[i]; }
  bA = bih[lane]; bB = bih[rowB];
}

__device__ __forceinline__ void load_rec_w(
    const float* __restrict__ whh, const float* __restrict__ bhh,
    int jq, int half, float4 Wr[3], float4 Wz[3], float4 Wn[3],
    float& bR, float& bZ, float& bN) {
  const float4* wr = reinterpret_cast<const float4*>(whh + jq * 24 + half * 12);
  const float4* wz = reinterpret_cast<const float4*>(whh + (24 + jq) * 24 + half * 12);
  const float4* wn = reinterpret_cast<const float4*>(whh + (48 + jq) * 24 + half * 12);
#pragma unroll
  for (int i = 0; i < 3; ++i) { Wr[i] = wr[i]; Wz[i] = wz[i]; Wn[i] = wn[i]; }
  bR = half ? 0.0f : bhh[jq];
  bZ = half ? 0.0f : bhh[24 + jq];
  bN = half ? 0.0f : bhh[48 + jq];
}

// ---- compute stages (weights already in regs) ----
__device__ __forceinline__ void gates_comp(
    const float4 WA[6], const float4 WB[6], float bA, float bB,
    const float* srcp, float* s_gi, int L, int lane) {
  int t = 0;
#pragma unroll 1
  for (; t + 1 < L; t += 2) {
    const float4* h0 = reinterpret_cast<const float4*>(srcp + t * 24);
    const float4* h1 = reinterpret_cast<const float4*>(srcp + t * 24 + 24);
    float a0 = bA, a1 = bA, c0 = bB, c1 = bB;
#pragma unroll
    for (int i = 0; i < 6; ++i) {
      float4 p = h0[i], q = h1[i], A = WA[i], Bv = WB[i];
      a0 = fmaf(A.x, p.x, a0); a0 = fmaf(A.y, p.y, a0);
      a0 = fmaf(A.z, p.z, a0); a0 = fmaf(A.w, p.w, a0);
      a1 = fmaf(A.x, q.x, a1); a1 = fmaf(A.y, q.y, a1);
      a1 = fmaf(A.z, q.z, a1); a1 = fmaf(A.w, q.w, a1);
      c0 = fmaf(Bv.x, p.x, c0); c0 = fmaf(Bv.y, p.y, c0);
      c0 = fmaf(Bv.z, p.z, c0); c0 = fmaf(Bv.w, p.w, c0);
      c1 = fmaf(Bv.x, q.x, c1); c1 = fmaf(Bv.y, q.y, c1);
      c1 = fmaf(Bv.z, q.z, c1); c1 = fmaf(Bv.w, q.w, c1);
    }
    s_gi[t * 72 + lane] = a0;
    s_gi[t * 72 + 72 + lane] = a1;
    if (lane < 8) {
      s_gi[t * 72 + 64 + lane] = c0;
      s_gi[t * 72 + 136 + lane] = c1;
    }
  }
  if (t < L) {
    const float4* h0 = reinterpret_cast<const float4*>(srcp + t * 24);
    float a0 = bA, c0 = bB;
#pragma unroll
    for (int i = 0; i < 6; ++i) {
      float4 p = h0[i], A = WA[i], Bv = WB[i];
      a0 = fmaf(A.x, p.x, a0); a0 = fmaf(A.y, p.y, a0);
      a0 = fmaf(A.z, p.z, a0); a0 = fmaf(A.w, p.w, a0);
      c0 = fmaf(Bv.x, p.x, c0); c0 = fmaf(Bv.y, p.y, c0);
      c0 = fmaf(Bv.z, p.z, c0); c0 = fmaf(Bv.w, p.w, c0);
    }
    s_gi[t * 72 + lane] = a0;
    if (lane < 8) s_gi[t * 72 + 64 + lane] = c0;
  }
}

__device__ __forceinline__ void rec_comp(
    const float4 Wr[3], const float4 Wz[3], const float4 Wn[3],
    float bR, float bZ, float bN,
    const float* s_gi, float* s_hid, float* s_y, int L, int lane, int jq, int half) {
  if (lane < 24) s_hid[lane] = 0.0f;
  int cur = 0;
#pragma unroll 1
  for (int t = 0; t < L; ++t) {
    const float4* hp = reinterpret_cast<const float4*>(s_hid + cur * 24 + half * 12);
    float gr = bR, gz = bZ, gn = bN;
#pragma unroll
    for (int i = 0; i < 3; ++i) {
      float4 hh = hp[i];
      gr = fmaf(Wr[i].x, hh.x, gr); gr = fmaf(Wr[i].y, hh.y, gr);
      gr = fmaf(Wr[i].z, hh.z, gr); gr = fmaf(Wr[i].w, hh.w, gr);
      gz = fmaf(Wz[i].x, hh.x, gz); gz = fmaf(Wz[i].y, hh.y, gz);
      gz = fmaf(Wz[i].z, hh.z, gz); gz = fmaf(Wz[i].w, hh.w, gz);
      gn = fmaf(Wn[i].x, hh.x, gn); gn = fmaf(Wn[i].y, hh.y, gn);
      gn = fmaf(Wn[i].z, hh.z, gn); gn = fmaf(Wn[i].w, hh.w, gn);
    }
    gr += __shfl_xor(gr, 32);
    gz += __shfl_xor(gz, 32);
    gn += __shfl_xor(gn, 32);
    const float* gi = s_gi + t * 72;
    float r   = sigm(gi[jq] + gr);
    float zg  = sigm(gi[24 + jq] + gz);
    float nn2 = tanh_fast(gi[48 + jq] + r * gn);
    float hold = s_hid[cur * 24 + jq];
    float hnew = fmaf(zg, hold - nn2, nn2);  // (1-z)*n + z*h
    if (lane < 24) {
      s_hid[(cur ^ 1) * 24 + lane] = hnew;
      s_y[t * 24 + lane] = hnew;
    }
    cur ^= 1;
  }
}

// ---- pre-kernel: fused gates-L0 weights per node into workspace ----
__global__ void fuse_kernel(const float* __restrict__ gru_wih,
                            const float* __restrict__ gru_bih,
                            const float* __restrict__ gpw,
                            const float* __restrict__ gpb,
                            float* __restrict__ fw, float* __restrict__ fb) {
  const int n = blockIdx.x;
  const int tid = threadIdx.x;
  const float* w = gru_wih + (size_t)(n * 2) * 1728;  // layer 0
  for (int it = tid; it < 1728; it += 64) {
    int r = it / 24, k = it - r * 24;
    float acc = 0.0f;
#pragma unroll
    for (int j = 0; j < 24; ++j) acc = fmaf(w[r * 24 + j], gpw[j * 24 + k], acc);
    fw[(size_t)n * 1728 + it] = acc;
  }
  for (int r = tid; r < 72; r += 64) {
    float acc = gru_bih[(n * 2) * 72 + r];
#pragma unroll
    for (int j = 0; j < 24; ++j) acc = fmaf(w[r * 24 + j], gpb[j], acc);
    fb[n * 72 + r] = acc;
  }
}

// LDS layout (floats). Total 4832 floats = 19,328 B.
//  s_h  [8][24] @128   s_gi [8][72] @320   s_y   [8][24] @896
//  s_hid[2][24] @1088  s_d1 [8][68] @1136  s_d2  [8][68] @1680
//  s_emb[8][8][8] @2528   s_pz [8][8][24] @3040   s_zz [8][32] @4576
__global__ __launch_bounds__(NT, 2) void tcm_kernel(
    const float* __restrict__ z,
    const float* __restrict__ cond_w1, const float* __restrict__ cond_b1,
    const float* __restrict__ cond_w2, const float* __restrict__ cond_b2,
    const float* __restrict__ proj_w, const float* __restrict__ proj_b,
    const float* __restrict__ gru_wih, const float* __restrict__ gru_whh,
    const float* __restrict__ gru_bih, const float* __restrict__ gru_bhh,
    const float* __restrict__ cm_w1, const float* __restrict__ cm_b1,
    const float* __restrict__ cm_w2, const float* __restrict__ cm_b2,
    const float* __restrict__ cm_w3, const float* __restrict__ cm_b3,
    const int* __restrict__ endw,
    const float* __restrict__ fw, const float* __restrict__ fb,
    float* __restrict__ out, int Btot) {
  __shared__ __align__(16) float lds[4832];
  float* s_h   = lds + 128;    // [8][24]
  float* s_gi  = lds + 320;    // [8][72]
  float* s_y   = lds + 896;    // [8][24]
  float* s_hid = lds + 1088;   // [2][24]
  float* s_d1  = lds + 1136;   // stride 68
  float* s_d2  = lds + 1680;   // stride 68
  float* s_emb = lds + 2528;   // [n][t][c] = n*64 + t*8 + c
  float* s_pz  = lds + 3040;   // [n][t][j] = n*192 + t*24 + j
  float* s_zz  = lds + 4576;   // [8][32] staging (idx==0 only)

  const int lane = threadIdx.x;
  const int b = blockIdx.x;
  const int T = endw[0];
  const int jm = lane & 31;
  const int half = lane >> 5;
  const int jq = jm < 24 ? jm : 0;
  const int rowB = 64 + (lane & 7);

#pragma unroll 1
  for (int idx = 0; idx < T; ++idx) {
    const int L = idx + 1;
#pragma unroll 1
    for (int n = 0; n < 8; ++n) {
      const float* wih1 = gru_wih + (size_t)(n * 2 + 1) * 1728;
      const float* whh0 = gru_whh + (size_t)(n * 2) * 1728;
      const float* whh1 = whh0 + 1728;
      const float* bih1 = gru_bih + (n * 2 + 1) * 72;
      const float* bhh0 = gru_bhh + (n * 2) * 72;
      const float* bhh1 = bhh0 + 72;

      // prefetch FUSED gates-L0 weights (used after proj)
      float4 WA[6], WB[6]; float bA, bB;
      load_gates_w(fw + (size_t)n * 1728, fb + n * 72, lane, rowB, WA, WB, bA, bB);

      // ---- idx==0: hoist proj's z-contribution for ALL 8 t rows
      if (idx == 0) {
        const float4* z4 = reinterpret_cast<const float4*>(
            z + ((size_t)n * Btot + b) * 8 * 32);
        reinterpret_cast<float4*>(s_zz)[lane] = z4[lane];
        SYNC();
#pragma unroll 1
        for (int it = lane; it < 192; it += NT) {
          int t = it / 24, j = it - t * 24;
          s_pz[n * 192 + t * 24 + j] =
              proj_b[n * 24 + j] +
              dotv2<8>(proj_w + (size_t)(n * 24 + j) * 48, s_zz + t * 32);
        }
        SYNC();
      }
      // ---- proj -> leaky: z-part from s_pz; emb-part direct from s_emb
#pragma unroll 1
      for (int it = lane; it < L * 24; it += NT) {
        int t = it / 24, j = it - t * 24;
        const float* pw = proj_w + (size_t)(n * 24 + j) * 48;
        float acc = s_pz[n * 192 + t * 24 + j];
        if (t < idx)
          acc += dotv2<2>(pw + 32, s_emb + n * 64 + t * 8);
        if (n > 0 && idx > 0)
          acc += dotv2<2>(pw + 40, s_emb + (n - 1) * 64 + t * 8);
        s_h[t * 24 + j] = leaky(acc);
      }
      SYNC();
      // prefetch rec-L0 weights (in flight during gates L0)
      float4 Wr[3], Wz[3], Wn[3]; float bR, bZ, bN;
      load_rec_w(whh0, bhh0, jq, half, Wr, Wz, Wn, bR, bZ, bN);
      // ---- gates L0 (FUSED: consumes s_h directly)
      gates_comp(WA, WB, bA, bB, s_h, s_gi, L, lane);
      SYNC();
      // prefetch gates-L1 weights (in flight during rec L0)
      float4 WA1[6], WB1[6]; float bA1, bB1;
      load_gates_w(wih1, bih1, lane, rowB, WA1, WB1, bA1, bB1);
      // ---- rec L0 -> s_y
      rec_comp(Wr, Wz, Wn, bR, bZ, bN, s_gi, s_hid, s_y, L, lane, jq, half);
      SYNC();
      // prefetch rec-L1 weights (in flight during gates L1)
      float4 Wr1[3], Wz1[3], Wn1[3]; float bR1, bZ1, bN1;
      load_rec_w(whh1, bhh1, jq, half, Wr1, Wz1, Wn1, bR1, bZ1, bN1);
      // ---- gates L1
      gates_comp(WA1, WB1, bA1, bB1, s_y, s_gi, L, lane);
      SYNC();
      // prefetch cm1 row (in flight during rec L1)
      float4 C1[6];
      {
        const float4* p = reinterpret_cast<const float4*>(
            cm_w1 + (size_t)(n * 64 + lane) * 24);
#pragma unroll
        for (int i = 0; i < 6; ++i) C1[i] = p[i];
      }
      const float c1b = cm_b1[n * 64 + lane];
      // ---- rec L1 -> s_y
      rec_comp(Wr1, Wz1, Wn1, bR1, bZ1, bN1, s_gi, s_hid, s_y, L, lane, jq, half);
      SYNC();
      // prefetch cm2 row (in flight during cm1)
      float4 C2[16];
      {
        const float4* p = reinterpret_cast<const float4*>(
            cm_w2 + (size_t)(n * 64 + lane) * 64);
#pragma unroll
        for (int i = 0; i < 16; ++i) C2[i] = p[i];
      }
      const float c2b = cm_b2[n * 64 + lane];
      // ---- cm1: lane = j, t unrolled by 2
      {
        int t = 0;
#pragma unroll 1
        for (; t + 1 < L; t += 2) {
          const float4* y0 = reinterpret_cast<const float4*>(s_y + t * 24);
          const float4* y1 = reinterpret_cast<const float4*>(s_y + t * 24 + 24);
          float a0 = c1b, a1 = c1b;
#pragma unroll
          for (int i = 0; i < 6; ++i) {
            float4 pp = y0[i], q = y1[i], W = C1[i];
            a0 = fmaf(W.x, pp.x, a0); a0 = fmaf(W.y, pp.y, a0);
            a0 = fmaf(W.z, pp.z, a0); a0 = fmaf(W.w, pp.w, a0);
            a1 = fmaf(W.x, q.x, a1); a1 = fmaf(W.y, q.y, a1);
            a1 = fmaf(W.z, q.z, a1); a1 = fmaf(W.w, q.w, a1);
          }
          s_d1[t * 68 + lane] = fmaxf(a0, 0.0f);
          s_d1[t * 68 + 68 + lane] = fmaxf(a1, 0.0f);
        }
        if (t < L) {
          float acc = c1b;
          const float4* y0 = reinterpret_cast<const float4*>(s_y + t * 24);
#pragma unroll
          for (int i = 0; i < 6; ++i) {
            float4 pp = y0[i], W = C1[i];
            acc = fmaf(W.x, pp.x, acc); acc = fmaf(W.y, pp.y, acc);
            acc = fmaf(W.z, pp.z, acc); acc = fmaf(W.w, pp.w, acc);
          }
          s_d1[t * 68 + lane] = fmaxf(acc, 0.0f);
        }
      }
      SYNC();
      // ---- cm2: lane = j, t unrolled by 2, 2 accs per t
      {
        int t = 0;
#pragma unroll 1
        for (; t + 1 < L; t += 2) {
          const float4* d0 = reinterpret_cast<const float4*>(s_d1 + t * 68);
          const float4* d1 = reinterpret_cast<const float4*>(s_d1 + t * 68 + 68);
          float a0 = c2b, a1 = 0.0f, c0 = c2b, c1 = 0.0f;
#pragma unroll
          for (int i = 0; i < 16; i += 2) {
            float4 W0 = C2[i], W1 = C2[i + 1];
            float4 p0 = d0[i], p1 = d0[i + 1], q0 = d1[i], q1 = d1[i + 1];
            a0 = fmaf(W0.x, p0.x, a0); a0 = fmaf(W0.y, p0.y, a0);
            a0 = fmaf(W0.z, p0.z, a0); a0 = fmaf(W0.w, p0.w, a0);
            a1 = fmaf(W1.x, p1.x, a1); a1 = fmaf(W1.y, p1.y, a1);
            a1 = fmaf(W1.z, p1.z, a1); a1 = fmaf(W1.w, p1.w, a1);
            c0 = fmaf(W0.x, q0.x, c0); c0 = fmaf(W0.y, q0.y, c0);
            c0 = fmaf(W0.z, q0.z, c0); c0 = fmaf(W0.w, q0.w, c0);
            c1 = fmaf(W1.x, q1.x, c1); c1 = fmaf(W1.y, q1.y, c1);
            c1 = fmaf(W1.z, q1.z, c1); c1 = fmaf(W1.w, q1.w, c1);
          }
          s_d2[t * 68 + lane] = fmaxf(a0 + a1, 0.0f);
          s_d2[t * 68 + 68 + lane] = fmaxf(c0 + c1, 0.0f);
        }
        if (t < L) {
          const float4* d0 = reinterpret_cast<const float4*>(s_d1 + t * 68);
          float a0 = c2b, a1 = 0.0f;
#pragma unroll
          for (int i = 0; i < 16; i += 2) {
            float4 W0 = C2[i], W1 = C2[i + 1];
            float4 p0 = d0[i], p1 = d0[i + 1];
            a0 = fmaf(W0.x, p0.x, a0); a0 = fmaf(W0.y, p0.y, a0);
            a0 = fmaf(W0.z, p0.z, a0); a0 = fmaf(W0.w, p0.w, a0);
            a1 = fmaf(W1.x, p1.x, a1); a1 = fmaf(W1.y, p1.y, a1);
            a1 = fmaf(W1.z, p1.z, a1); a1 = fmaf(W1.w, p1.w, a1);
          }
          s_d2[t * 68 + lane] = fmaxf(a0 + a1, 0.0f);
        }
      }
      SYNC();
      // ---- cm3 + cond FUSED: lane (t,c) recomputes dv_t from s_d2
      //      (8 lanes/t read the same row = LDS broadcast, free), then
      //      emb = b2[c] + sum_k w2[c][k]*relu(dv*w1[k]+b1[k]).
      //      s_dd round-trip + 1 SYNC eliminated; wave-issue count equal
      //      to the old serial cm3+cond (issue cost is per-wave).
      if (lane < L * 8) {
        int t = lane >> 3, c = lane & 7;
        float dv = cm_b3[n] + dotv4<16>(cm_w3 + n * 64, s_d2 + t * 68);
        if (t == idx && c == 0)
          out[((size_t)b * T + idx) * 8 + n] = dv;
        const float* w1 = cond_w1 + n * 32;
        const float* b1 = cond_b1 + n * 32;
        const float4* w2 = reinterpret_cast<const float4*>(
            cond_w2 + (size_t)(n * 8 + c) * 32);
        float acc = cond_b2[n * 8 + c];
#pragma unroll
        for (int i = 0; i < 8; ++i) {
          float4 wv = w2[i];
          float h0 = fmaxf(fmaf(dv, w1[4 * i + 0], b1[4 * i + 0]), 0.0f);
          float h1 = fmaxf(fmaf(dv, w1[4 * i + 1], b1[4 * i + 1]), 0.0f);
          float h2 = fmaxf(fmaf(dv, w1[4 * i + 2], b1[4 * i + 2]), 0.0f);
          float h3 = fmaxf(fmaf(dv, w1[4 * i + 3], b1[4 * i + 3]), 0.0f);
          acc = fmaf(wv.x, h0, acc); acc = fmaf(wv.y, h1, acc);
          acc = fmaf(wv.z, h2, acc); acc = fmaf(wv.w, h3, acc);
        }
        s_emb[n * 64 + t * 8 + c] = acc;
      }
      SYNC();
    }
  }
}

extern "C" void kernel_launch(void* const* d_in, const int* in_sizes, int n_in,
                              void* d_out, int out_size, void* d_ws, size_t ws_size,
                              hipStream_t stream) {
  const float* z       = (const float*)d_in[0];
  const float* cond_w1 = (const float*)d_in[1];
  const float* cond_b1 = (const float*)d_in[2];
  const float* cond_w2 = (const float*)d_in[3];
  const float* cond_b2 = (const float*)d_in[4];
  const float* proj_w  = (const float*)d_in[5];
  const float* proj_b  = (const float*)d_in[6];
  const float* gpw     = (const float*)d_in[7];
  const float* gpb     = (const float*)d_in[8];
  const float* gru_wih = (const float*)d_in[9];
  const float* gru_whh = (const float*)d_in[10];
  const float* gru_bih = (const float*)d_in[11];
  const float* gru_bhh = (const float*)d_in[12];
  const float* cm_w1   = (const float*)d_in[13];
  const float* cm_b1   = (const float*)d_in[14];
  const float* cm_w2   = (const float*)d_in[15];
  const float* cm_b2   = (const float*)d_in[16];
  const float* cm_w3   = (const float*)d_in[17];
  const float* cm_b3   = (const float*)d_in[18];
  const int*   endw    = (const int*)d_in[19];
  float* out = (float*)d_out;

  int Btot = in_sizes[0] / (8 * 8 * 32);  // z: [8, B, 8, 32]

  // workspace: fused gates-L0 weights [8][72][24] + bias [8][72]
  float* fw = (float*)d_ws;            // 8*1728 floats
  float* fb = fw + 8 * 1728;           // 8*72 floats (total 57.6 KB)

  fuse_kernel<<<8, 64, 0, stream>>>(gru_wih, gru_bih, gpw, gpb, fw, fb);

  tcm_kernel<<<Btot, NT, 0, stream>>>(
      z, cond_w1, cond_b1, cond_w2, cond_b2, proj_w, proj_b,
      gru_wih, gru_whh, gru_bih, gru_bhh, cm_w1, cm_b1, cm_w2, cm_b2,
      cm_w3, cm_b3, endw, fw, fb, out, Btot);
}